// Round 5
// baseline (281.375 us; speedup 1.0000x reference)
//
#include <hip/hip_runtime.h>
#include <math.h>

#define HW   4096
#define CIN  256
#define ICH  128
#define NB   4
#define KSPL 8
#define KVB  32
#define TILES 16   // 512 keys per split / 32

typedef __attribute__((ext_vector_type(4))) float f32x4;
typedef __attribute__((ext_vector_type(8))) short bf16x8;
typedef __attribute__((ext_vector_type(4))) short bf16x4;
typedef __attribute__((ext_vector_type(4))) unsigned u32x4;

__device__ inline short f2bf(float f) {
    unsigned int u = __float_as_uint(f);
    u += 0x7fffU + ((u >> 16) & 1U);   // round-to-nearest-even
    return (short)(u >> 16);
}

__device__ inline float bf2f(short s) {
    return __uint_as_float(((unsigned int)(unsigned short)s) << 16);
}

__device__ inline float exp2a(float x) {  // 2^x, handles -inf -> 0
    float r;
    asm("v_exp_f32 %0, %1" : "=v"(r) : "v"(x));
    return r;
}
__device__ inline float log2a(float x) {
    float r;
    asm("v_log_f32 %0, %1" : "=v"(r) : "v"(x));
    return r;
}
__device__ inline unsigned cvtpk(float a, float b) {  // lo=bf16(a), hi=bf16(b), RNE
    unsigned r;
    asm("v_cvt_pk_bf16_f32 %0, %1, %2" : "=v"(r) : "v"(a), "v"(b));
    return r;
}

__device__ inline f32x4 mfma16(bf16x8 a, bf16x8 b, f32x4 c) {
    return __builtin_amdgcn_mfma_f32_16x16x32_bf16(a, b, c, 0, 0, 0);
}

__device__ inline bf16x8 ldf(const short* p) { return *(const bf16x8*)p; }

// ---------------------------------------------------------------------------
// K0: weights -> bf16; fold BN params. Theta's BN scale/bias folded with
// log2(e) so attention logits are base-2.
// ---------------------------------------------------------------------------
__global__ void k_prep_w(const float* __restrict__ wth, const float* __restrict__ wph,
                         const float* __restrict__ wg,  const float* __restrict__ ww,
                         const float* __restrict__ gth, const float* __restrict__ bth,
                         const float* __restrict__ mth, const float* __restrict__ vth,
                         const float* __restrict__ gph, const float* __restrict__ bph,
                         const float* __restrict__ mph, const float* __restrict__ vph,
                         short* __restrict__ wthb, short* __restrict__ wphb,
                         short* __restrict__ wgb,  short* __restrict__ wwb,
                         float* __restrict__ bnp) {
    const float LOG2E = 1.44269504f;
    int i = blockIdx.x * 256 + threadIdx.x;
    wthb[i] = f2bf(wth[i]);
    wphb[i] = f2bf(wph[i]);
    wgb[i]  = f2bf(wg[i]);
    wwb[i]  = f2bf(ww[i]);
    if (blockIdx.x == 0 && threadIdx.x < ICH) {
        int o = threadIdx.x;
        float s1 = gth[o] * rsqrtf(vth[o] + 1e-5f);
        bnp[o]        = s1 * LOG2E;
        bnp[ICH + o]  = (bth[o] - mth[o] * s1) * LOG2E;
        float s2 = gph[o] * rsqrtf(vph[o] + 1e-5f);
        bnp[2*ICH + o] = s2;
        bnp[3*ICH + o] = bph[o] - mph[o] * s2;
    }
}

// ---------------------------------------------------------------------------
// K1: x = max_d(feature), cx = feature[:, :, 5]; write (n,q,c) bf16.
// ---------------------------------------------------------------------------
__global__ __launch_bounds__(256) void k_prep_x(const float* __restrict__ feat,
                                                short* __restrict__ Xbf,
                                                short* __restrict__ CXbf) {
    const int q0 = blockIdx.x * 64;
    const int c0 = blockIdx.y * 32;
    const int n  = blockIdx.z;
    __shared__ float xs[32][68];
    __shared__ float cxs[32][68];
    const int tid = threadIdx.x;
    const int qv  = (tid & 15) * 4;
    const int ci  = tid >> 4;          // 0..15

    #pragma unroll
    for (int h = 0; h < 2; ++h) {
        const int cc = h * 16 + ci;
        const float* fp = feat + ((size_t)(n * CIN + c0 + cc)) * 9 * HW + q0 + qv;
        float4 mx = *(const float4*)fp;
        float4 cx = make_float4(0.f, 0.f, 0.f, 0.f);
        #pragma unroll
        for (int d = 1; d < 9; ++d) {
            float4 v = *(const float4*)(fp + (size_t)d * HW);
            if (d == 5) cx = v;
            mx.x = fmaxf(mx.x, v.x); mx.y = fmaxf(mx.y, v.y);
            mx.z = fmaxf(mx.z, v.z); mx.w = fmaxf(mx.w, v.w);
        }
        *(float4*)&xs[cc][qv]  = mx;
        *(float4*)&cxs[cc][qv] = cx;
    }
    __syncthreads();
    #pragma unroll
    for (int it = 0; it < 2; ++it) {
        const int q  = it * 32 + (tid >> 3);
        const int cq = (tid & 7) * 4;
        ushort4 ox, oc;
        ox.x = (unsigned short)f2bf(xs[cq][q]);
        ox.y = (unsigned short)f2bf(xs[cq + 1][q]);
        ox.z = (unsigned short)f2bf(xs[cq + 2][q]);
        ox.w = (unsigned short)f2bf(xs[cq + 3][q]);
        oc.x = (unsigned short)f2bf(cxs[cq][q]);
        oc.y = (unsigned short)f2bf(cxs[cq + 1][q]);
        oc.z = (unsigned short)f2bf(cxs[cq + 2][q]);
        oc.w = (unsigned short)f2bf(cxs[cq + 3][q]);
        const size_t ob = ((size_t)n * HW + q0 + q) * CIN + c0 + cq;
        *(ushort4*)&Xbf[ob]  = ox;
        *(ushort4*)&CXbf[ob] = oc;
    }
}

// ---------------------------------------------------------------------------
// K2: theta/phi (q,c) with BN+ReLU (theta pre-scaled by log2e via bnp);
//     g with swapped roles -> Vt (c,k).
// ---------------------------------------------------------------------------
__global__ __launch_bounds__(256) void k_conv3(const short* __restrict__ Xbf,
                                               const short* __restrict__ CXbf,
                                               const short* __restrict__ wthb,
                                               const short* __restrict__ wphb,
                                               const short* __restrict__ wgb,
                                               const float* __restrict__ bnp,
                                               short* __restrict__ theta,
                                               short* __restrict__ phi,
                                               short* __restrict__ Vt) {
    const int n    = blockIdx.y;
    const int wave = threadIdx.x >> 6;
    const int lane = threadIdx.x & 63;
    const int lr = lane & 15, lg = lane >> 4;
    const int q0 = blockIdx.x * 64 + wave * 16;
    const short* Xn  = Xbf  + (size_t)n * HW * CIN;
    const short* CXn = CXbf + (size_t)n * HW * CIN;
    short* thn = theta + (size_t)n * HW * ICH;
    short* phn = phi   + (size_t)n * HW * ICH;
    short* vtn = Vt    + (size_t)n * ICH * HW;

    f32x4 acc[8];
    #pragma unroll
    for (int i = 0; i < 8; ++i) { acc[i][0]=0.f; acc[i][1]=0.f; acc[i][2]=0.f; acc[i][3]=0.f; }
    #pragma unroll
    for (int cf = 0; cf < 8; ++cf) {
        bf16x8 a = ldf(CXn + (q0 + lr) * CIN + cf * 32 + lg * 8);
        #pragma unroll
        for (int of = 0; of < 8; ++of) {
            bf16x8 b = ldf(wthb + (of * 16 + lr) * CIN + cf * 32 + lg * 8);
            acc[of] = mfma16(a, b, acc[of]);
        }
    }
    #pragma unroll
    for (int of = 0; of < 8; ++of) {
        int o = of * 16 + lr;
        float sA = bnp[o], sB = bnp[ICH + o];
        #pragma unroll
        for (int r = 0; r < 4; ++r) {
            int q = q0 + lg * 4 + r;
            thn[q * ICH + o] = f2bf(fmaxf(acc[of][r] * sA + sB, 0.f));
        }
    }

    #pragma unroll
    for (int i = 0; i < 8; ++i) { acc[i][0]=0.f; acc[i][1]=0.f; acc[i][2]=0.f; acc[i][3]=0.f; }
    #pragma unroll
    for (int cf = 0; cf < 8; ++cf) {
        bf16x8 a = ldf(Xn + (q0 + lr) * CIN + cf * 32 + lg * 8);
        #pragma unroll
        for (int of = 0; of < 8; ++of) {
            bf16x8 b = ldf(wphb + (of * 16 + lr) * CIN + cf * 32 + lg * 8);
            acc[of] = mfma16(a, b, acc[of]);
        }
    }
    #pragma unroll
    for (int of = 0; of < 8; ++of) {
        int o = of * 16 + lr;
        float sA = bnp[2*ICH + o], sB = bnp[3*ICH + o];
        #pragma unroll
        for (int r = 0; r < 4; ++r) {
            int q = q0 + lg * 4 + r;
            phn[q * ICH + o] = f2bf(fmaxf(acc[of][r] * sA + sB, 0.f));
        }
    }

    #pragma unroll
    for (int i = 0; i < 8; ++i) { acc[i][0]=0.f; acc[i][1]=0.f; acc[i][2]=0.f; acc[i][3]=0.f; }
    #pragma unroll
    for (int cf = 0; cf < 8; ++cf) {
        bf16x8 bx = ldf(Xn + (q0 + lr) * CIN + cf * 32 + lg * 8);
        #pragma unroll
        for (int mf = 0; mf < 8; ++mf) {
            bf16x8 a = ldf(wgb + (mf * 16 + lr) * CIN + cf * 32 + lg * 8);
            acc[mf] = mfma16(a, bx, acc[mf]);
        }
    }
    #pragma unroll
    for (int mf = 0; mf < 8; ++mf) {
        #pragma unroll
        for (int r = 0; r < 4; ++r) {
            int o = mf * 16 + lg * 4 + r;
            vtn[(size_t)o * HW + q0 + lr] = f2bf(acc[mf][r]);
        }
    }
}

// ---------------------------------------------------------------------------
// K3: flash attention, k-split x8, swapped-operand QK^T, lane-local softmax,
// in-register P via v_cvt_pk_bf16_f32. NO LDS, NO barriers: K and V fragments
// are read directly from global (K/V per batch = 2MB, L2-resident; 4 waves
// per block walk the same k-chunk so L1 catches the reuse). Waves free-run ->
// heterogeneous phase overlap across 12 waves/CU.
// grid 1024 x 256 (4 waves x 32 q). XCD mapping: n = (bid&7)>>1.
// ---------------------------------------------------------------------------
__global__ __launch_bounds__(256, 3) void k_attn(const short* __restrict__ theta,
                                                 const short* __restrict__ phi,
                                                 const short* __restrict__ Vt,
                                                 short* __restrict__ Op,
                                                 float* __restrict__ Ls) {
    const int bid  = blockIdx.x;
    const int j    = bid & 7;
    const int n    = j >> 1;
    const int rest = ((bid >> 3) << 1) | (j & 1);   // 0..255
    const int qb   = rest >> 3;                     // 0..31
    const int ks   = rest & 7;                      // 0..7
    const int tid  = threadIdx.x;
    const int wave = tid >> 6;
    const int lane = tid & 63;
    const int lr = lane & 15, lg = lane >> 4;
    const int q0 = qb * 128 + wave * 32;
    const int kbase = ks * 512;

    const short* Qn = theta + (size_t)n * HW * ICH;
    const short* Kn = phi   + (size_t)n * HW * ICH;
    const short* Vn = Vt    + (size_t)n * ICH * HW;

    bf16x8 aq[2][4];
    #pragma unroll
    for (int m2 = 0; m2 < 2; ++m2)
        #pragma unroll
        for (int cf = 0; cf < 4; ++cf)
            aq[m2][cf] = ldf(Qn + (q0 + m2 * 16 + lr) * ICH + cf * 32 + lg * 8);

    // O^T accumulators: O[m2][cc] rows c = cc*16+lg*4+r, col q = q0+m2*16+lr
    f32x4 O[2][8];
    #pragma unroll
    for (int m2 = 0; m2 < 2; ++m2)
        #pragma unroll
        for (int i = 0; i < 8; ++i) { O[m2][i][0]=0.f; O[m2][i][1]=0.f; O[m2][i][2]=0.f; O[m2][i][3]=0.f; }
    float mx[2] = { -INFINITY, -INFINITY };
    float l[2]  = { 0.f, 0.f };

    for (int t = 0; t < TILES; ++t) {
        const short* Kt = Kn + (size_t)(kbase + t * KVB) * ICH;
        const short* Vb = Vn + kbase + t * KVB;

        // ---- S^T = K Q^T : 8 global b128 loads + 16 MFMA
        f32x4 s[2][2];
        #pragma unroll
        for (int tt = 0; tt < 2; ++tt)
            #pragma unroll
            for (int m2 = 0; m2 < 2; ++m2) { s[tt][m2][0]=0.f; s[tt][m2][1]=0.f; s[tt][m2][2]=0.f; s[tt][m2][3]=0.f; }
        __builtin_amdgcn_s_setprio(1);
        #pragma unroll
        for (int tt = 0; tt < 2; ++tt) {
            #pragma unroll
            for (int cf = 0; cf < 4; ++cf) {
                bf16x8 kf = ldf(Kt + (tt * 16 + lr) * ICH + cf * 32 + lg * 8);
                s[tt][0] = mfma16(kf, aq[0][cf], s[tt][0]);
                s[tt][1] = mfma16(kf, aq[1][cf], s[tt][1]);
            }
        }
        __builtin_amdgcn_s_setprio(0);

        // ---- lane-local softmax (base-2, defer-max THR=11)
        float lm[2];
        #pragma unroll
        for (int m2 = 0; m2 < 2; ++m2) {
            float a0 = fmaxf(fmaxf(s[0][m2][0], s[0][m2][1]), fmaxf(s[0][m2][2], s[0][m2][3]));
            float a1 = fmaxf(fmaxf(s[1][m2][0], s[1][m2][1]), fmaxf(s[1][m2][2], s[1][m2][3]));
            lm[m2] = fmaxf(a0, a1);
        }
        int need = (lm[0] > mx[0] + 11.f) || (lm[1] > mx[1] + 11.f);
        if (__any(need)) {
            #pragma unroll
            for (int m2 = 0; m2 < 2; ++m2) {
                float v = lm[m2];
                v = fmaxf(v, __shfl_xor(v, 16));
                v = fmaxf(v, __shfl_xor(v, 32));
                float mn = fmaxf(mx[m2], v);
                float a  = exp2a(mx[m2] - mn);
                mx[m2] = mn;
                l[m2] *= a;
                #pragma unroll
                for (int cc = 0; cc < 8; ++cc) {
                    O[m2][cc][0] *= a; O[m2][cc][1] *= a;
                    O[m2][cc][2] *= a; O[m2][cc][3] *= a;
                }
            }
        }
        // P fragments in-register: slots 0-3 <- tt0 (keys lg*4+r), 4-7 <- tt1
        bf16x8 pb[2];
        #pragma unroll
        for (int m2 = 0; m2 < 2; ++m2) {
            float e[8];
            #pragma unroll
            for (int r = 0; r < 4; ++r) {
                e[r]     = exp2a(s[0][m2][r] - mx[m2]);
                e[4 + r] = exp2a(s[1][m2][r] - mx[m2]);
            }
            l[m2] += ((e[0] + e[1]) + (e[2] + e[3])) + ((e[4] + e[5]) + (e[6] + e[7]));
            union { u32x4 u; bf16x8 b; } cv;
            cv.u[0] = cvtpk(e[0], e[1]);
            cv.u[1] = cvtpk(e[2], e[3]);
            cv.u[2] = cvtpk(e[4], e[5]);
            cv.u[3] = cvtpk(e[6], e[7]);
            pb[m2] = cv.b;
        }

        // ---- O^T += V^T P^T : 16 global b64 loads + 16 MFMA
        __builtin_amdgcn_s_setprio(1);
        #pragma unroll
        for (int cc = 0; cc < 8; ++cc) {
            const short* vb = Vb + (size_t)(cc * 16 + lr) * HW + lg * 4;
            bf16x4 va0 = *(const bf16x4*)vb;         // keys lg*4 + 0..3
            bf16x4 va1 = *(const bf16x4*)(vb + 16);  // keys 16 + lg*4 + 0..3
            bf16x8 vf = __builtin_shufflevector(va0, va1, 0, 1, 2, 3, 4, 5, 6, 7);
            O[0][cc] = mfma16(vf, pb[0], O[0][cc]);
            O[1][cc] = mfma16(vf, pb[1], O[1][cc]);
        }
        __builtin_amdgcn_s_setprio(0);
    }

    // ---- epilogue: reduce l across lg groups, write partial + lse2
    const size_t obase = (size_t)(ks * NB + n) * HW;
    #pragma unroll
    for (int m2 = 0; m2 < 2; ++m2) {
        float v = l[m2];
        v += __shfl_xor(v, 16);
        v += __shfl_xor(v, 32);
        l[m2] = v;
        const float inv = 1.f / v;
        const int q = q0 + m2 * 16 + lr;
        #pragma unroll
        for (int cc = 0; cc < 8; ++cc) {
            uint2 ov;
            ov.x = cvtpk(O[m2][cc][0] * inv, O[m2][cc][1] * inv);
            ov.y = cvtpk(O[m2][cc][2] * inv, O[m2][cc][3] * inv);
            *(uint2*)&Op[(obase + q) * ICH + cc * 16 + lg * 4] = ov;
        }
        if (lg == 0)
            Ls[obase + q] = mx[m2] + log2a(l[m2]);
    }
}

// ---------------------------------------------------------------------------
// K4: fused combine + final conv + residual.
// Phase 1: 256 threads cooperatively combine the 8 k-split partials into an
// XOR-swizzled LDS tile (combine done ONCE, not per-wave). Phase 2: MFMA.
// grid (128, 4) x 256.
// ---------------------------------------------------------------------------
__global__ __launch_bounds__(256) void k_out(const short* __restrict__ Op,
                                             const float* __restrict__ Ls,
                                             const short* __restrict__ wwb,
                                             const float* __restrict__ feat,
                                             float* __restrict__ out) {
    __shared__ char bo_lds[32 * 256];   // 32 q x 128 c bf16, rows 256B, XOR-swizzled
    const int n   = blockIdx.y;
    const int q0  = blockIdx.x * 32;
    const int tid = threadIdx.x;

    // ---- phase 1: combine splits for (q = tid>>3, c = (tid&7)*16 .. +16)
    {
        const int q  = tid >> 3;
        const int c0 = (tid & 7) * 16;
        const int qg = q0 + q;
        float ls[KSPL], M = -INFINITY;
        #pragma unroll
        for (int i = 0; i < KSPL; ++i) {
            ls[i] = Ls[((size_t)(i * NB + n)) * HW + qg];
            M = fmaxf(M, ls[i]);
        }
        float wq[KSPL], ws = 0.f;
        #pragma unroll
        for (int i = 0; i < KSPL; ++i) { wq[i] = exp2a(ls[i] - M); ws += wq[i]; }
        const float inv = 1.f / ws;
        float fo[16];
        #pragma unroll
        for (int e = 0; e < 16; ++e) fo[e] = 0.f;
        #pragma unroll
        for (int i = 0; i < KSPL; ++i) {
            const short* p = Op + ((size_t)(i * NB + n) * HW + qg) * ICH + c0;
            bf16x8 v0 = ldf(p);
            bf16x8 v1 = ldf(p + 8);
            #pragma unroll
            for (int e = 0; e < 8; ++e) {
                fo[e]     += wq[i] * bf2f(v0[e]);
                fo[8 + e] += wq[i] * bf2f(v1[e]);
            }
        }
        const int rsw = (q & 7) << 4;
        u32x4 w0, w1;
        #pragma unroll
        for (int e = 0; e < 4; ++e) {
            w0[e] = cvtpk(fo[2*e] * inv,     fo[2*e+1] * inv);
            w1[e] = cvtpk(fo[8+2*e] * inv,   fo[8+2*e+1] * inv);
        }
        *(u32x4*)&bo_lds[q * 256 + ((c0 * 2) ^ rsw)]        = w0;
        *(u32x4*)&bo_lds[q * 256 + (((c0 + 8) * 2) ^ rsw)]  = w1;
    }
    __syncthreads();

    // ---- phase 2: out[o, q] = ww @ bO + residual
    const int wave = tid >> 6;
    const int lane = tid & 63;
    const int lr = lane & 15, lg = lane >> 4;
    const int o0 = wave * 64;

    f32x4 acc[4][2];
    #pragma unroll
    for (int i = 0; i < 4; ++i)
        #pragma unroll
        for (int jn = 0; jn < 2; ++jn) { acc[i][jn][0]=0.f; acc[i][jn][1]=0.f; acc[i][jn][2]=0.f; acc[i][jn][3]=0.f; }

    #pragma unroll
    for (int cf = 0; cf < 4; ++cf) {
        bf16x8 bO[2];
        #pragma unroll
        for (int nf = 0; nf < 2; ++nf) {
            const int row = nf * 16 + lr;
            const int byt = (cf * 64 + lg * 16) ^ ((row & 7) << 4);
            bO[nf] = *(const bf16x8*)&bo_lds[row * 256 + byt];
        }
        #pragma unroll
        for (int mf = 0; mf < 4; ++mf) {
            bf16x8 a = ldf(wwb + (o0 + mf * 16 + lr) * ICH + cf * 32 + lg * 8);
            #pragma unroll
            for (int nf = 0; nf < 2; ++nf)
                acc[mf][nf] = mfma16(a, bO[nf], acc[mf][nf]);
        }
    }
    #pragma unroll
    for (int mf = 0; mf < 4; ++mf) {
        #pragma unroll
        for (int nf = 0; nf < 2; ++nf) {
            #pragma unroll
            for (int r = 0; r < 4; ++r) {
                int o = o0 + mf * 16 + lg * 4 + r;
                int q = q0 + nf * 16 + lr;
                long long cxi = (((long long)(n * CIN + o)) * 9 + 5) * HW + q;
                out[((long long)(n * CIN + o)) * HW + q] = acc[mf][nf][r] + feat[cxi];
            }
        }
    }
}

// ---------------------------------------------------------------------------
extern "C" void kernel_launch(void* const* d_in, const int* in_sizes, int n_in,
                              void* d_out, int out_size, void* d_ws, size_t ws_size,
                              hipStream_t stream) {
    const float* feat = (const float*)d_in[0];
    const float* wth  = (const float*)d_in[1];
    const float* gth  = (const float*)d_in[2];
    const float* bth  = (const float*)d_in[3];
    const float* mth  = (const float*)d_in[4];
    const float* vth  = (const float*)d_in[5];
    const float* wph  = (const float*)d_in[6];
    const float* gph  = (const float*)d_in[7];
    const float* bph  = (const float*)d_in[8];
    const float* mph  = (const float*)d_in[9];
    const float* vph  = (const float*)d_in[10];
    const float* wg   = (const float*)d_in[11];
    const float* ww   = (const float*)d_in[12];
    float* out = (float*)d_out;

    size_t off = 0;
    auto carve = [&](size_t bytes) {
        void* p = (char*)d_ws + off;
        off += (bytes + 255) & ~(size_t)255;
        return p;
    };
    short* Xbf   = (short*)carve((size_t)NB * HW * CIN * 2);
    short* CXbf  = (short*)carve((size_t)NB * HW * CIN * 2);
    short* theta = (short*)carve((size_t)NB * HW * ICH * 2);
    short* phi   = (short*)carve((size_t)NB * HW * ICH * 2);
    short* Vt    = (short*)carve((size_t)NB * ICH * HW * 2);
    short* Op    = (short*)carve((size_t)KSPL * NB * HW * ICH * 2);
    float* Ls    = (float*)carve((size_t)KSPL * NB * HW * 4);
    short* wthb  = (short*)carve((size_t)ICH * CIN * 2);
    short* wphb  = (short*)carve((size_t)ICH * CIN * 2);
    short* wgb   = (short*)carve((size_t)ICH * CIN * 2);
    short* wwb   = (short*)carve((size_t)CIN * ICH * 2);
    float* bnp   = (float*)carve((size_t)4 * ICH * 4);

    k_prep_w<<<128, 256, 0, stream>>>(wth, wph, wg, ww, gth, bth, mth, vth,
                                      gph, bph, mph, vph, wthb, wphb, wgb, wwb, bnp);
    k_prep_x<<<dim3(64, 8, NB), 256, 0, stream>>>(feat, Xbf, CXbf);
    k_conv3<<<dim3(64, NB), 256, 0, stream>>>(Xbf, CXbf, wthb, wphb, wgb, bnp,
                                              theta, phi, Vt);
    k_attn<<<1024, 256, 0, stream>>>(theta, phi, Vt, Op, Ls);
    k_out<<<dim3(128, NB), 256, 0, stream>>>(Op, Ls, wwb, feat, out);
}

// Round 6
// 219.647 us; speedup vs baseline: 1.2810x; 1.2810x over previous
//
#include <hip/hip_runtime.h>
#include <math.h>

#define HW   4096
#define CIN  256
#define ICH  128
#define NB   4
#define KSPL 8
#define KVB  32
#define TILES 16   // 512 keys per split / 32

typedef __attribute__((ext_vector_type(4))) float f32x4;
typedef __attribute__((ext_vector_type(8))) short bf16x8;
typedef __attribute__((ext_vector_type(4))) short bf16x4;
typedef __attribute__((ext_vector_type(4))) unsigned u32x4;

typedef const __attribute__((address_space(1))) void* gptr_t;
typedef __attribute__((address_space(3))) void* lptr_t;

__device__ inline short f2bf(float f) {
    unsigned int u = __float_as_uint(f);
    u += 0x7fffU + ((u >> 16) & 1U);   // round-to-nearest-even
    return (short)(u >> 16);
}

__device__ inline float bf2f(short s) {
    return __uint_as_float(((unsigned int)(unsigned short)s) << 16);
}

__device__ inline float exp2a(float x) {  // 2^x, handles -inf -> 0
    float r;
    asm("v_exp_f32 %0, %1" : "=v"(r) : "v"(x));
    return r;
}
__device__ inline float log2a(float x) {
    float r;
    asm("v_log_f32 %0, %1" : "=v"(r) : "v"(x));
    return r;
}
__device__ inline unsigned cvtpk(float a, float b) {  // lo=bf16(a), hi=bf16(b), RNE
    unsigned r;
    asm("v_cvt_pk_bf16_f32 %0, %1, %2" : "=v"(r) : "v"(a), "v"(b));
    return r;
}

__device__ inline f32x4 mfma16(bf16x8 a, bf16x8 b, f32x4 c) {
    return __builtin_amdgcn_mfma_f32_16x16x32_bf16(a, b, c, 0, 0, 0);
}

__device__ inline bf16x8 ldf(const short* p) { return *(const bf16x8*)p; }

// ---------------------------------------------------------------------------
// K0: weights -> bf16; fold BN params. Theta's BN scale/bias folded with
// log2(e) so attention logits are base-2.
// ---------------------------------------------------------------------------
__global__ void k_prep_w(const float* __restrict__ wth, const float* __restrict__ wph,
                         const float* __restrict__ wg,  const float* __restrict__ ww,
                         const float* __restrict__ gth, const float* __restrict__ bth,
                         const float* __restrict__ mth, const float* __restrict__ vth,
                         const float* __restrict__ gph, const float* __restrict__ bph,
                         const float* __restrict__ mph, const float* __restrict__ vph,
                         short* __restrict__ wthb, short* __restrict__ wphb,
                         short* __restrict__ wgb,  short* __restrict__ wwb,
                         float* __restrict__ bnp) {
    const float LOG2E = 1.44269504f;
    int i = blockIdx.x * 256 + threadIdx.x;
    wthb[i] = f2bf(wth[i]);
    wphb[i] = f2bf(wph[i]);
    wgb[i]  = f2bf(wg[i]);
    wwb[i]  = f2bf(ww[i]);
    if (blockIdx.x == 0 && threadIdx.x < ICH) {
        int o = threadIdx.x;
        float s1 = gth[o] * rsqrtf(vth[o] + 1e-5f);
        bnp[o]        = s1 * LOG2E;
        bnp[ICH + o]  = (bth[o] - mth[o] * s1) * LOG2E;
        float s2 = gph[o] * rsqrtf(vph[o] + 1e-5f);
        bnp[2*ICH + o] = s2;
        bnp[3*ICH + o] = bph[o] - mph[o] * s2;
    }
}

// ---------------------------------------------------------------------------
// K1: x = max_d(feature), cx = feature[:, :, 5]; write (n,q,c) bf16.
// ---------------------------------------------------------------------------
__global__ __launch_bounds__(256) void k_prep_x(const float* __restrict__ feat,
                                                short* __restrict__ Xbf,
                                                short* __restrict__ CXbf) {
    const int q0 = blockIdx.x * 64;
    const int c0 = blockIdx.y * 32;
    const int n  = blockIdx.z;
    __shared__ float xs[32][68];
    __shared__ float cxs[32][68];
    const int tid = threadIdx.x;
    const int qv  = (tid & 15) * 4;
    const int ci  = tid >> 4;          // 0..15

    #pragma unroll
    for (int h = 0; h < 2; ++h) {
        const int cc = h * 16 + ci;
        const float* fp = feat + ((size_t)(n * CIN + c0 + cc)) * 9 * HW + q0 + qv;
        float4 mx = *(const float4*)fp;
        float4 cx = make_float4(0.f, 0.f, 0.f, 0.f);
        #pragma unroll
        for (int d = 1; d < 9; ++d) {
            float4 v = *(const float4*)(fp + (size_t)d * HW);
            if (d == 5) cx = v;
            mx.x = fmaxf(mx.x, v.x); mx.y = fmaxf(mx.y, v.y);
            mx.z = fmaxf(mx.z, v.z); mx.w = fmaxf(mx.w, v.w);
        }
        *(float4*)&xs[cc][qv]  = mx;
        *(float4*)&cxs[cc][qv] = cx;
    }
    __syncthreads();
    #pragma unroll
    for (int it = 0; it < 2; ++it) {
        const int q  = it * 32 + (tid >> 3);
        const int cq = (tid & 7) * 4;
        ushort4 ox, oc;
        ox.x = (unsigned short)f2bf(xs[cq][q]);
        ox.y = (unsigned short)f2bf(xs[cq + 1][q]);
        ox.z = (unsigned short)f2bf(xs[cq + 2][q]);
        ox.w = (unsigned short)f2bf(xs[cq + 3][q]);
        oc.x = (unsigned short)f2bf(cxs[cq][q]);
        oc.y = (unsigned short)f2bf(cxs[cq + 1][q]);
        oc.z = (unsigned short)f2bf(cxs[cq + 2][q]);
        oc.w = (unsigned short)f2bf(cxs[cq + 3][q]);
        const size_t ob = ((size_t)n * HW + q0 + q) * CIN + c0 + cq;
        *(ushort4*)&Xbf[ob]  = ox;
        *(ushort4*)&CXbf[ob] = oc;
    }
}

// ---------------------------------------------------------------------------
// K2: theta/phi (q,c) with BN+ReLU (theta pre-scaled by log2e via bnp);
//     g with swapped roles -> Vt (c,k).
// ---------------------------------------------------------------------------
__global__ __launch_bounds__(256) void k_conv3(const short* __restrict__ Xbf,
                                               const short* __restrict__ CXbf,
                                               const short* __restrict__ wthb,
                                               const short* __restrict__ wphb,
                                               const short* __restrict__ wgb,
                                               const float* __restrict__ bnp,
                                               short* __restrict__ theta,
                                               short* __restrict__ phi,
                                               short* __restrict__ Vt) {
    const int n    = blockIdx.y;
    const int wave = threadIdx.x >> 6;
    const int lane = threadIdx.x & 63;
    const int lr = lane & 15, lg = lane >> 4;
    const int q0 = blockIdx.x * 64 + wave * 16;
    const short* Xn  = Xbf  + (size_t)n * HW * CIN;
    const short* CXn = CXbf + (size_t)n * HW * CIN;
    short* thn = theta + (size_t)n * HW * ICH;
    short* phn = phi   + (size_t)n * HW * ICH;
    short* vtn = Vt    + (size_t)n * ICH * HW;

    f32x4 acc[8];
    #pragma unroll
    for (int i = 0; i < 8; ++i) { acc[i][0]=0.f; acc[i][1]=0.f; acc[i][2]=0.f; acc[i][3]=0.f; }
    #pragma unroll
    for (int cf = 0; cf < 8; ++cf) {
        bf16x8 a = ldf(CXn + (q0 + lr) * CIN + cf * 32 + lg * 8);
        #pragma unroll
        for (int of = 0; of < 8; ++of) {
            bf16x8 b = ldf(wthb + (of * 16 + lr) * CIN + cf * 32 + lg * 8);
            acc[of] = mfma16(a, b, acc[of]);
        }
    }
    #pragma unroll
    for (int of = 0; of < 8; ++of) {
        int o = of * 16 + lr;
        float sA = bnp[o], sB = bnp[ICH + o];
        #pragma unroll
        for (int r = 0; r < 4; ++r) {
            int q = q0 + lg * 4 + r;
            thn[q * ICH + o] = f2bf(fmaxf(acc[of][r] * sA + sB, 0.f));
        }
    }

    #pragma unroll
    for (int i = 0; i < 8; ++i) { acc[i][0]=0.f; acc[i][1]=0.f; acc[i][2]=0.f; acc[i][3]=0.f; }
    #pragma unroll
    for (int cf = 0; cf < 8; ++cf) {
        bf16x8 a = ldf(Xn + (q0 + lr) * CIN + cf * 32 + lg * 8);
        #pragma unroll
        for (int of = 0; of < 8; ++of) {
            bf16x8 b = ldf(wphb + (of * 16 + lr) * CIN + cf * 32 + lg * 8);
            acc[of] = mfma16(a, b, acc[of]);
        }
    }
    #pragma unroll
    for (int of = 0; of < 8; ++of) {
        int o = of * 16 + lr;
        float sA = bnp[2*ICH + o], sB = bnp[3*ICH + o];
        #pragma unroll
        for (int r = 0; r < 4; ++r) {
            int q = q0 + lg * 4 + r;
            phn[q * ICH + o] = f2bf(fmaxf(acc[of][r] * sA + sB, 0.f));
        }
    }

    #pragma unroll
    for (int i = 0; i < 8; ++i) { acc[i][0]=0.f; acc[i][1]=0.f; acc[i][2]=0.f; acc[i][3]=0.f; }
    #pragma unroll
    for (int cf = 0; cf < 8; ++cf) {
        bf16x8 bx = ldf(Xn + (q0 + lr) * CIN + cf * 32 + lg * 8);
        #pragma unroll
        for (int mf = 0; mf < 8; ++mf) {
            bf16x8 a = ldf(wgb + (mf * 16 + lr) * CIN + cf * 32 + lg * 8);
            acc[mf] = mfma16(a, bx, acc[mf]);
        }
    }
    #pragma unroll
    for (int mf = 0; mf < 8; ++mf) {
        #pragma unroll
        for (int r = 0; r < 4; ++r) {
            int o = mf * 16 + lg * 4 + r;
            vtn[(size_t)o * HW + q0 + lr] = f2bf(acc[mf][r]);
        }
    }
}

// ---------------------------------------------------------------------------
// K3: flash attention, k-split x8, swapped-operand QK^T (S^T = mfma(K,Q)) ->
// lane-local softmax + in-register P (cvt_pk). K double-buffered via
// global_load_lds (XOR-swizzled source, linear dest); V reg-staged into
// 80B-stride LDS (conflict-free). One barrier per 32-key tile.
// __launch_bounds__(256,4): LDS 36.9KB + VGPR<=128 -> 4 blocks/CU, and the
// 1024-block grid is exactly 4x256 -> all blocks co-resident (zero tail);
// cross-block phase diversity covers the per-tile barrier/vmcnt drains.
// grid 1024 x 256 (4 waves x 32 q). XCD mapping: n = (bid&7)>>1.
// ---------------------------------------------------------------------------
__global__ __launch_bounds__(256, 4) void k_attn(const short* __restrict__ theta,
                                                 const short* __restrict__ phi,
                                                 const short* __restrict__ Vt,
                                                 short* __restrict__ Op,
                                                 float* __restrict__ Ls) {
    __shared__ char  K_lds[2][8192];        // 32 keys x 128 ch bf16, XOR-swizzled
    __shared__ short V_lds[2][128 * 40];    // 128 ch x 32 keys, stride 40 shorts

    const int bid  = blockIdx.x;
    const int j    = bid & 7;
    const int n    = j >> 1;
    const int rest = ((bid >> 3) << 1) | (j & 1);   // 0..255
    const int qb   = rest >> 3;                     // 0..31
    const int ks   = rest & 7;                      // 0..7
    const int tid  = threadIdx.x;
    const int wave = tid >> 6;
    const int lane = tid & 63;
    const int lr = lane & 15, lg = lane >> 4;
    const int q0 = qb * 128 + wave * 32;
    const int kbase = ks * 512;

    const short* Qn = theta + (size_t)n * HW * ICH;
    const short* Kn = phi   + (size_t)n * HW * ICH;
    const short* Vn = Vt    + (size_t)n * ICH * HW;

    bf16x8 aq[2][4];
    #pragma unroll
    for (int m2 = 0; m2 < 2; ++m2)
        #pragma unroll
        for (int cf = 0; cf < 4; ++cf)
            aq[m2][cf] = ldf(Qn + (q0 + m2 * 16 + lr) * ICH + cf * 32 + lg * 8);

    // O^T accumulators: O[m2][cc] rows c = cc*16+lg*4+r, col q = q0+m2*16+lr
    f32x4 O[2][8];
    #pragma unroll
    for (int m2 = 0; m2 < 2; ++m2)
        #pragma unroll
        for (int i = 0; i < 8; ++i) { O[m2][i][0]=0.f; O[m2][i][1]=0.f; O[m2][i][2]=0.f; O[m2][i][3]=0.f; }
    float mx[2] = { -INFINITY, -INFINITY };
    float l[2]  = { 0.f, 0.f };

    bf16x8 vr0, vr1;
    auto stageK = [&](int tt, int pp) {
        #pragma unroll
        for (int i = 0; i < 2; ++i) {
            const int o   = wave * 2048 + i * 1024 + lane * 16;  // linear dest byte
            const int row = o >> 8;
            const int cb  = (o & 255) ^ ((row & 7) << 4);
            const char* src = (const char*)Kn + (size_t)(kbase + tt * KVB + row) * 256 + cb;
            __builtin_amdgcn_global_load_lds((gptr_t)src,
                (lptr_t)(&K_lds[pp][wave * 2048 + i * 1024]), 16, 0, 0);
        }
    };
    auto loadV = [&](int tt) {
        vr0 = ldf(Vn + (size_t)(tid >> 2) * HW + kbase + tt * KVB + (tid & 3) * 8);
        vr1 = ldf(Vn + (size_t)((tid + 256) >> 2) * HW + kbase + tt * KVB + (tid & 3) * 8);
    };
    auto writeV = [&](int pp) {
        *(bf16x8*)&V_lds[pp][(tid >> 2) * 40 + (tid & 3) * 8] = vr0;
        *(bf16x8*)&V_lds[pp][((tid + 256) >> 2) * 40 + (tid & 3) * 8] = vr1;
    };

    stageK(0, 0);
    loadV(0);
    writeV(0);
    __syncthreads();

    for (int t = 0; t < TILES; ++t) {
        const int p = t & 1;
        const bool pre = (t + 1 < TILES);
        if (pre) { stageK(t + 1, p ^ 1); loadV(t + 1); }

        // ---- S^T = K Q^T : rows = keys, cols = q. s[tt][m2]
        f32x4 s[2][2];
        #pragma unroll
        for (int tt = 0; tt < 2; ++tt)
            #pragma unroll
            for (int m2 = 0; m2 < 2; ++m2) { s[tt][m2][0]=0.f; s[tt][m2][1]=0.f; s[tt][m2][2]=0.f; s[tt][m2][3]=0.f; }
        __builtin_amdgcn_s_setprio(1);
        #pragma unroll
        for (int tt = 0; tt < 2; ++tt) {
            const int row = tt * 16 + lr;
            const int rsw = (row & 7) << 4;
            #pragma unroll
            for (int cf = 0; cf < 4; ++cf) {
                bf16x8 kf = *(const bf16x8*)(&K_lds[p][row * 256 + ((cf * 64 + lg * 16) ^ rsw)]);
                s[tt][0] = mfma16(kf, aq[0][cf], s[tt][0]);
                s[tt][1] = mfma16(kf, aq[1][cf], s[tt][1]);
            }
        }
        __builtin_amdgcn_s_setprio(0);

        // ---- lane-local softmax (base-2, defer-max THR=11)
        float lm[2];
        #pragma unroll
        for (int m2 = 0; m2 < 2; ++m2) {
            float a0 = fmaxf(fmaxf(s[0][m2][0], s[0][m2][1]), fmaxf(s[0][m2][2], s[0][m2][3]));
            float a1 = fmaxf(fmaxf(s[1][m2][0], s[1][m2][1]), fmaxf(s[1][m2][2], s[1][m2][3]));
            lm[m2] = fmaxf(a0, a1);
        }
        int need = (lm[0] > mx[0] + 11.f) || (lm[1] > mx[1] + 11.f);
        if (__any(need)) {
            #pragma unroll
            for (int m2 = 0; m2 < 2; ++m2) {
                float v = lm[m2];
                v = fmaxf(v, __shfl_xor(v, 16));
                v = fmaxf(v, __shfl_xor(v, 32));
                float mn = fmaxf(mx[m2], v);
                float a  = exp2a(mx[m2] - mn);
                mx[m2] = mn;
                l[m2] *= a;
                #pragma unroll
                for (int cc = 0; cc < 8; ++cc) {
                    O[m2][cc][0] *= a; O[m2][cc][1] *= a;
                    O[m2][cc][2] *= a; O[m2][cc][3] *= a;
                }
            }
        }
        // P fragments in-register: slots 0-3 <- tt0 (keys lg*4+r), 4-7 <- tt1
        bf16x8 pb[2];
        #pragma unroll
        for (int m2 = 0; m2 < 2; ++m2) {
            float e[8];
            #pragma unroll
            for (int r = 0; r < 4; ++r) {
                e[r]     = exp2a(s[0][m2][r] - mx[m2]);
                e[4 + r] = exp2a(s[1][m2][r] - mx[m2]);
            }
            l[m2] += ((e[0] + e[1]) + (e[2] + e[3])) + ((e[4] + e[5]) + (e[6] + e[7]));
            union { u32x4 u; bf16x8 b; } cv;
            cv.u[0] = cvtpk(e[0], e[1]);
            cv.u[1] = cvtpk(e[2], e[3]);
            cv.u[2] = cvtpk(e[4], e[5]);
            cv.u[3] = cvtpk(e[6], e[7]);
            pb[m2] = cv.b;
        }

        // ---- O^T += V^T P^T : A = V-frag (same k-permutation), B = P
        __builtin_amdgcn_s_setprio(1);
        #pragma unroll
        for (int cc = 0; cc < 8; ++cc) {
            const short* vb = &V_lds[p][(cc * 16 + lr) * 40 + lg * 4];
            bf16x4 va0 = *(const bf16x4*)vb;         // keys lg*4 + 0..3
            bf16x4 va1 = *(const bf16x4*)(vb + 16);  // keys 16 + lg*4 + 0..3
            bf16x8 vf = __builtin_shufflevector(va0, va1, 0, 1, 2, 3, 4, 5, 6, 7);
            O[0][cc] = mfma16(vf, pb[0], O[0][cc]);
            O[1][cc] = mfma16(vf, pb[1], O[1][cc]);
        }
        __builtin_amdgcn_s_setprio(0);

        if (pre) writeV(p ^ 1);
        __syncthreads();
    }

    // ---- epilogue: reduce l across lg groups, write partial + lse2
    const size_t obase = (size_t)(ks * NB + n) * HW;
    #pragma unroll
    for (int m2 = 0; m2 < 2; ++m2) {
        float v = l[m2];
        v += __shfl_xor(v, 16);
        v += __shfl_xor(v, 32);
        l[m2] = v;
        const float inv = 1.f / v;
        const int q = q0 + m2 * 16 + lr;
        #pragma unroll
        for (int cc = 0; cc < 8; ++cc) {
            uint2 ov;
            ov.x = cvtpk(O[m2][cc][0] * inv, O[m2][cc][1] * inv);
            ov.y = cvtpk(O[m2][cc][2] * inv, O[m2][cc][3] * inv);
            *(uint2*)&Op[(obase + q) * ICH + cc * 16 + lg * 4] = ov;
        }
        if (lg == 0)
            Ls[obase + q] = mx[m2] + log2a(l[m2]);
    }
}

// ---------------------------------------------------------------------------
// K4: fused combine + final conv + residual.
// Phase 1: 256 threads cooperatively combine the 8 k-split partials into an
// XOR-swizzled LDS tile (combine done ONCE, not per-wave). Phase 2: MFMA.
// grid (128, 4) x 256.
// ---------------------------------------------------------------------------
__global__ __launch_bounds__(256) void k_out(const short* __restrict__ Op,
                                             const float* __restrict__ Ls,
                                             const short* __restrict__ wwb,
                                             const float* __restrict__ feat,
                                             float* __restrict__ out) {
    __shared__ char bo_lds[32 * 256];   // 32 q x 128 c bf16, rows 256B, XOR-swizzled
    const int n   = blockIdx.y;
    const int q0  = blockIdx.x * 32;
    const int tid = threadIdx.x;

    // ---- phase 1: combine splits for (q = tid>>3, c = (tid&7)*16 .. +16)
    {
        const int q  = tid >> 3;
        const int c0 = (tid & 7) * 16;
        const int qg = q0 + q;
        float ls[KSPL], M = -INFINITY;
        #pragma unroll
        for (int i = 0; i < KSPL; ++i) {
            ls[i] = Ls[((size_t)(i * NB + n)) * HW + qg];
            M = fmaxf(M, ls[i]);
        }
        float wq[KSPL], ws = 0.f;
        #pragma unroll
        for (int i = 0; i < KSPL; ++i) { wq[i] = exp2a(ls[i] - M); ws += wq[i]; }
        const float inv = 1.f / ws;
        float fo[16];
        #pragma unroll
        for (int e = 0; e < 16; ++e) fo[e] = 0.f;
        #pragma unroll
        for (int i = 0; i < KSPL; ++i) {
            const short* p = Op + ((size_t)(i * NB + n) * HW + qg) * ICH + c0;
            bf16x8 v0 = ldf(p);
            bf16x8 v1 = ldf(p + 8);
            #pragma unroll
            for (int e = 0; e < 8; ++e) {
                fo[e]     += wq[i] * bf2f(v0[e]);
                fo[8 + e] += wq[i] * bf2f(v1[e]);
            }
        }
        const int rsw = (q & 7) << 4;
        u32x4 w0, w1;
        #pragma unroll
        for (int e = 0; e < 4; ++e) {
            w0[e] = cvtpk(fo[2*e] * inv,     fo[2*e+1] * inv);
            w1[e] = cvtpk(fo[8+2*e] * inv,   fo[8+2*e+1] * inv);
        }
        *(u32x4*)&bo_lds[q * 256 + ((c0 * 2) ^ rsw)]        = w0;
        *(u32x4*)&bo_lds[q * 256 + (((c0 + 8) * 2) ^ rsw)]  = w1;
    }
    __syncthreads();

    // ---- phase 2: out[o, q] = ww @ bO + residual
    const int wave = tid >> 6;
    const int lane = tid & 63;
    const int lr = lane & 15, lg = lane >> 4;
    const int o0 = wave * 64;

    f32x4 acc[4][2];
    #pragma unroll
    for (int i = 0; i < 4; ++i)
        #pragma unroll
        for (int jn = 0; jn < 2; ++jn) { acc[i][jn][0]=0.f; acc[i][jn][1]=0.f; acc[i][jn][2]=0.f; acc[i][jn][3]=0.f; }

    #pragma unroll
    for (int cf = 0; cf < 4; ++cf) {
        bf16x8 bO[2];
        #pragma unroll
        for (int nf = 0; nf < 2; ++nf) {
            const int row = nf * 16 + lr;
            const int byt = (cf * 64 + lg * 16) ^ ((row & 7) << 4);
            bO[nf] = *(const bf16x8*)&bo_lds[row * 256 + byt];
        }
        #pragma unroll
        for (int mf = 0; mf < 4; ++mf) {
            bf16x8 a = ldf(wwb + (o0 + mf * 16 + lr) * ICH + cf * 32 + lg * 8);
            #pragma unroll
            for (int nf = 0; nf < 2; ++nf)
                acc[mf][nf] = mfma16(a, bO[nf], acc[mf][nf]);
        }
    }
    #pragma unroll
    for (int mf = 0; mf < 4; ++mf) {
        #pragma unroll
        for (int nf = 0; nf < 2; ++nf) {
            #pragma unroll
            for (int r = 0; r < 4; ++r) {
                int o = o0 + mf * 16 + lg * 4 + r;
                int q = q0 + nf * 16 + lr;
                long long cxi = (((long long)(n * CIN + o)) * 9 + 5) * HW + q;
                out[((long long)(n * CIN + o)) * HW + q] = acc[mf][nf][r] + feat[cxi];
            }
        }
    }
}

// ---------------------------------------------------------------------------
extern "C" void kernel_launch(void* const* d_in, const int* in_sizes, int n_in,
                              void* d_out, int out_size, void* d_ws, size_t ws_size,
                              hipStream_t stream) {
    const float* feat = (const float*)d_in[0];
    const float* wth  = (const float*)d_in[1];
    const float* gth  = (const float*)d_in[2];
    const float* bth  = (const float*)d_in[3];
    const float* mth  = (const float*)d_in[4];
    const float* vth  = (const float*)d_in[5];
    const float* wph  = (const float*)d_in[6];
    const float* gph  = (const float*)d_in[7];
    const float* bph  = (const float*)d_in[8];
    const float* mph  = (const float*)d_in[9];
    const float* vph  = (const float*)d_in[10];
    const float* wg   = (const float*)d_in[11];
    const float* ww   = (const float*)d_in[12];
    float* out = (float*)d_out;

    size_t off = 0;
    auto carve = [&](size_t bytes) {
        void* p = (char*)d_ws + off;
        off += (bytes + 255) & ~(size_t)255;
        return p;
    };
    short* Xbf   = (short*)carve((size_t)NB * HW * CIN * 2);
    short* CXbf  = (short*)carve((size_t)NB * HW * CIN * 2);
    short* theta = (short*)carve((size_t)NB * HW * ICH * 2);
    short* phi   = (short*)carve((size_t)NB * HW * ICH * 2);
    short* Vt    = (short*)carve((size_t)NB * ICH * HW * 2);
    short* Op    = (short*)carve((size_t)KSPL * NB * HW * ICH * 2);
    float* Ls    = (float*)carve((size_t)KSPL * NB * HW * 4);
    short* wthb  = (short*)carve((size_t)ICH * CIN * 2);
    short* wphb  = (short*)carve((size_t)ICH * CIN * 2);
    short* wgb   = (short*)carve((size_t)ICH * CIN * 2);
    short* wwb   = (short*)carve((size_t)CIN * ICH * 2);
    float* bnp   = (float*)carve((size_t)4 * ICH * 4);

    k_prep_w<<<128, 256, 0, stream>>>(wth, wph, wg, ww, gth, bth, mth, vth,
                                      gph, bph, mph, vph, wthb, wphb, wgb, wwb, bnp);
    k_prep_x<<<dim3(64, 8, NB), 256, 0, stream>>>(feat, Xbf, CXbf);
    k_conv3<<<dim3(64, NB), 256, 0, stream>>>(Xbf, CXbf, wthb, wphb, wgb, bnp,
                                              theta, phi, Vt);
    k_attn<<<1024, 256, 0, stream>>>(theta, phi, Vt, Op, Ls);
    k_out<<<dim3(128, NB), 256, 0, stream>>>(Op, Ls, wwb, feat, out);
}

// Round 7
// 146.781 us; speedup vs baseline: 1.9170x; 1.4964x over previous
//
#include <hip/hip_runtime.h>
#include <math.h>

#define HW   4096
#define CIN  256
#define ICH  128
#define NB   4
#define KSPL 8
#define KVB  32
#define TILES 16   // 512 keys per split / 32

typedef __attribute__((ext_vector_type(4))) float f32x4;
typedef __attribute__((ext_vector_type(8))) short bf16x8;
typedef __attribute__((ext_vector_type(4))) short bf16x4;
typedef __attribute__((ext_vector_type(4))) unsigned u32x4;

__device__ inline short f2bf(float f) {
    unsigned int u = __float_as_uint(f);
    u += 0x7fffU + ((u >> 16) & 1U);   // round-to-nearest-even
    return (short)(u >> 16);
}

__device__ inline float bf2f(short s) {
    return __uint_as_float(((unsigned int)(unsigned short)s) << 16);
}

__device__ inline float exp2a(float x) {  // 2^x, handles -inf -> 0
    float r;
    asm("v_exp_f32 %0, %1" : "=v"(r) : "v"(x));
    return r;
}
__device__ inline float log2a(float x) {
    float r;
    asm("v_log_f32 %0, %1" : "=v"(r) : "v"(x));
    return r;
}
__device__ inline unsigned cvtpk(float a, float b) {  // lo=bf16(a), hi=bf16(b), RNE
    unsigned r;
    asm("v_cvt_pk_bf16_f32 %0, %1, %2" : "=v"(r) : "v"(a), "v"(b));
    return r;
}

__device__ inline f32x4 mfma16(bf16x8 a, bf16x8 b, f32x4 c) {
    return __builtin_amdgcn_mfma_f32_16x16x32_bf16(a, b, c, 0, 0, 0);
}

__device__ inline bf16x8 ldf(const short* p) { return *(const bf16x8*)p; }

// ---------------------------------------------------------------------------
// K0: weights -> bf16; fold BN params. Theta's BN scale/bias folded with
// log2(e) so attention logits are base-2.
// ---------------------------------------------------------------------------
__global__ void k_prep_w(const float* __restrict__ wth, const float* __restrict__ wph,
                         const float* __restrict__ wg,  const float* __restrict__ ww,
                         const float* __restrict__ gth, const float* __restrict__ bth,
                         const float* __restrict__ mth, const float* __restrict__ vth,
                         const float* __restrict__ gph, const float* __restrict__ bph,
                         const float* __restrict__ mph, const float* __restrict__ vph,
                         short* __restrict__ wthb, short* __restrict__ wphb,
                         short* __restrict__ wgb,  short* __restrict__ wwb,
                         float* __restrict__ bnp) {
    const float LOG2E = 1.44269504f;
    int i = blockIdx.x * 256 + threadIdx.x;
    wthb[i] = f2bf(wth[i]);
    wphb[i] = f2bf(wph[i]);
    wgb[i]  = f2bf(wg[i]);
    wwb[i]  = f2bf(ww[i]);
    if (blockIdx.x == 0 && threadIdx.x < ICH) {
        int o = threadIdx.x;
        float s1 = gth[o] * rsqrtf(vth[o] + 1e-5f);
        bnp[o]        = s1 * LOG2E;
        bnp[ICH + o]  = (bth[o] - mth[o] * s1) * LOG2E;
        float s2 = gph[o] * rsqrtf(vph[o] + 1e-5f);
        bnp[2*ICH + o] = s2;
        bnp[3*ICH + o] = bph[o] - mph[o] * s2;
    }
}

// ---------------------------------------------------------------------------
// K1: x = max_d(feature), cx = feature[:, :, 5]; write (n,q,c) bf16.
// ---------------------------------------------------------------------------
__global__ __launch_bounds__(256) void k_prep_x(const float* __restrict__ feat,
                                                short* __restrict__ Xbf,
                                                short* __restrict__ CXbf) {
    const int q0 = blockIdx.x * 64;
    const int c0 = blockIdx.y * 32;
    const int n  = blockIdx.z;
    __shared__ float xs[32][68];
    __shared__ float cxs[32][68];
    const int tid = threadIdx.x;
    const int qv  = (tid & 15) * 4;
    const int ci  = tid >> 4;          // 0..15

    #pragma unroll
    for (int h = 0; h < 2; ++h) {
        const int cc = h * 16 + ci;
        const float* fp = feat + ((size_t)(n * CIN + c0 + cc)) * 9 * HW + q0 + qv;
        float4 mx = *(const float4*)fp;
        float4 cx = make_float4(0.f, 0.f, 0.f, 0.f);
        #pragma unroll
        for (int d = 1; d < 9; ++d) {
            float4 v = *(const float4*)(fp + (size_t)d * HW);
            if (d == 5) cx = v;
            mx.x = fmaxf(mx.x, v.x); mx.y = fmaxf(mx.y, v.y);
            mx.z = fmaxf(mx.z, v.z); mx.w = fmaxf(mx.w, v.w);
        }
        *(float4*)&xs[cc][qv]  = mx;
        *(float4*)&cxs[cc][qv] = cx;
    }
    __syncthreads();
    #pragma unroll
    for (int it = 0; it < 2; ++it) {
        const int q  = it * 32 + (tid >> 3);
        const int cq = (tid & 7) * 4;
        ushort4 ox, oc;
        ox.x = (unsigned short)f2bf(xs[cq][q]);
        ox.y = (unsigned short)f2bf(xs[cq + 1][q]);
        ox.z = (unsigned short)f2bf(xs[cq + 2][q]);
        ox.w = (unsigned short)f2bf(xs[cq + 3][q]);
        oc.x = (unsigned short)f2bf(cxs[cq][q]);
        oc.y = (unsigned short)f2bf(cxs[cq + 1][q]);
        oc.z = (unsigned short)f2bf(cxs[cq + 2][q]);
        oc.w = (unsigned short)f2bf(cxs[cq + 3][q]);
        const size_t ob = ((size_t)n * HW + q0 + q) * CIN + c0 + cq;
        *(ushort4*)&Xbf[ob]  = ox;
        *(ushort4*)&CXbf[ob] = oc;
    }
}

// ---------------------------------------------------------------------------
// K2: theta/phi (q,c) with BN+ReLU (theta pre-scaled by log2e via bnp);
//     g with swapped roles -> Vt (c,k).
// ---------------------------------------------------------------------------
__global__ __launch_bounds__(256) void k_conv3(const short* __restrict__ Xbf,
                                               const short* __restrict__ CXbf,
                                               const short* __restrict__ wthb,
                                               const short* __restrict__ wphb,
                                               const short* __restrict__ wgb,
                                               const float* __restrict__ bnp,
                                               short* __restrict__ theta,
                                               short* __restrict__ phi,
                                               short* __restrict__ Vt) {
    const int n    = blockIdx.y;
    const int wave = threadIdx.x >> 6;
    const int lane = threadIdx.x & 63;
    const int lr = lane & 15, lg = lane >> 4;
    const int q0 = blockIdx.x * 64 + wave * 16;
    const short* Xn  = Xbf  + (size_t)n * HW * CIN;
    const short* CXn = CXbf + (size_t)n * HW * CIN;
    short* thn = theta + (size_t)n * HW * ICH;
    short* phn = phi   + (size_t)n * HW * ICH;
    short* vtn = Vt    + (size_t)n * ICH * HW;

    f32x4 acc[8];
    #pragma unroll
    for (int i = 0; i < 8; ++i) { acc[i][0]=0.f; acc[i][1]=0.f; acc[i][2]=0.f; acc[i][3]=0.f; }
    #pragma unroll
    for (int cf = 0; cf < 8; ++cf) {
        bf16x8 a = ldf(CXn + (q0 + lr) * CIN + cf * 32 + lg * 8);
        #pragma unroll
        for (int of = 0; of < 8; ++of) {
            bf16x8 b = ldf(wthb + (of * 16 + lr) * CIN + cf * 32 + lg * 8);
            acc[of] = mfma16(a, b, acc[of]);
        }
    }
    #pragma unroll
    for (int of = 0; of < 8; ++of) {
        int o = of * 16 + lr;
        float sA = bnp[o], sB = bnp[ICH + o];
        #pragma unroll
        for (int r = 0; r < 4; ++r) {
            int q = q0 + lg * 4 + r;
            thn[q * ICH + o] = f2bf(fmaxf(acc[of][r] * sA + sB, 0.f));
        }
    }

    #pragma unroll
    for (int i = 0; i < 8; ++i) { acc[i][0]=0.f; acc[i][1]=0.f; acc[i][2]=0.f; acc[i][3]=0.f; }
    #pragma unroll
    for (int cf = 0; cf < 8; ++cf) {
        bf16x8 a = ldf(Xn + (q0 + lr) * CIN + cf * 32 + lg * 8);
        #pragma unroll
        for (int of = 0; of < 8; ++of) {
            bf16x8 b = ldf(wphb + (of * 16 + lr) * CIN + cf * 32 + lg * 8);
            acc[of] = mfma16(a, b, acc[of]);
        }
    }
    #pragma unroll
    for (int of = 0; of < 8; ++of) {
        int o = of * 16 + lr;
        float sA = bnp[2*ICH + o], sB = bnp[3*ICH + o];
        #pragma unroll
        for (int r = 0; r < 4; ++r) {
            int q = q0 + lg * 4 + r;
            phn[q * ICH + o] = f2bf(fmaxf(acc[of][r] * sA + sB, 0.f));
        }
    }

    #pragma unroll
    for (int i = 0; i < 8; ++i) { acc[i][0]=0.f; acc[i][1]=0.f; acc[i][2]=0.f; acc[i][3]=0.f; }
    #pragma unroll
    for (int cf = 0; cf < 8; ++cf) {
        bf16x8 bx = ldf(Xn + (q0 + lr) * CIN + cf * 32 + lg * 8);
        #pragma unroll
        for (int mf = 0; mf < 8; ++mf) {
            bf16x8 a = ldf(wgb + (mf * 16 + lr) * CIN + cf * 32 + lg * 8);
            acc[mf] = mfma16(a, bx, acc[mf]);
        }
    }
    #pragma unroll
    for (int mf = 0; mf < 8; ++mf) {
        #pragma unroll
        for (int r = 0; r < 4; ++r) {
            int o = mf * 16 + lg * 4 + r;
            vtn[(size_t)o * HW + q0 + lr] = f2bf(acc[mf][r]);
        }
    }
}

// ---------------------------------------------------------------------------
// K3: flash attention, k-split x8, swapped-operand QK^T (S^T = mfma(K,Q)) ->
// lane-local softmax + in-register P (cvt_pk). BOTH K and V are reg-staged
// (T14 issue-early / write-late): global b128 loads issued at loop top,
// ds_writes after PV, one barrier per tile with nothing left to drain.
// K LDS XOR-swizzled (write-side swz + read-side swz pair); V 80B-stride.
// grid 1024 x 256 (4 waves x 32 q). XCD mapping: n = (bid&7)>>1.
// ---------------------------------------------------------------------------
__global__ __launch_bounds__(256, 3) void k_attn(const short* __restrict__ theta,
                                                 const short* __restrict__ phi,
                                                 const short* __restrict__ Vt,
                                                 short* __restrict__ Op,
                                                 float* __restrict__ Ls) {
    __shared__ char  K_lds[2][8192];        // 32 keys x 128 ch bf16, XOR-swizzled
    __shared__ short V_lds[2][128 * 40];    // 128 ch x 32 keys, stride 40 shorts

    const int bid  = blockIdx.x;
    const int j    = bid & 7;
    const int n    = j >> 1;
    const int rest = ((bid >> 3) << 1) | (j & 1);   // 0..255
    const int qb   = rest >> 3;                     // 0..31
    const int ks   = rest & 7;                      // 0..7
    const int tid  = threadIdx.x;
    const int wave = tid >> 6;
    const int lane = tid & 63;
    const int lr = lane & 15, lg = lane >> 4;
    const int q0 = qb * 128 + wave * 32;
    const int kbase = ks * 512;

    const short* Qn = theta + (size_t)n * HW * ICH;
    const short* Kn = phi   + (size_t)n * HW * ICH;
    const short* Vn = Vt    + (size_t)n * ICH * HW;

    bf16x8 aq[2][4];
    #pragma unroll
    for (int m2 = 0; m2 < 2; ++m2)
        #pragma unroll
        for (int cf = 0; cf < 4; ++cf)
            aq[m2][cf] = ldf(Qn + (q0 + m2 * 16 + lr) * ICH + cf * 32 + lg * 8);

    // O^T accumulators: O[m2][cc] rows c = cc*16+lg*4+r, col q = q0+m2*16+lr
    f32x4 O[2][8];
    #pragma unroll
    for (int m2 = 0; m2 < 2; ++m2)
        #pragma unroll
        for (int i = 0; i < 8; ++i) { O[m2][i][0]=0.f; O[m2][i][1]=0.f; O[m2][i][2]=0.f; O[m2][i][3]=0.f; }
    float mx[2] = { -INFINITY, -INFINITY };
    float l[2]  = { 0.f, 0.f };

    bf16x8 kr0, kr1, vr0, vr1;
    auto loadK = [&](int tt) {   // linear coalesced b128; swizzle applied on WRITE
        const char* kc = (const char*)(Kn + (size_t)(kbase + tt * KVB) * ICH);
        kr0 = *(const bf16x8*)(kc + tid * 16);
        kr1 = *(const bf16x8*)(kc + 4096 + tid * 16);
    };
    auto writeK = [&](int pp) {
        const int o0 = tid * 16;
        const int o1 = 4096 + tid * 16;
        *(bf16x8*)&K_lds[pp][o0 ^ (((o0 >> 8) & 7) << 4)] = kr0;
        *(bf16x8*)&K_lds[pp][o1 ^ (((o1 >> 8) & 7) << 4)] = kr1;
    };
    auto loadV = [&](int tt) {
        vr0 = ldf(Vn + (size_t)(tid >> 2) * HW + kbase + tt * KVB + (tid & 3) * 8);
        vr1 = ldf(Vn + (size_t)((tid + 256) >> 2) * HW + kbase + tt * KVB + (tid & 3) * 8);
    };
    auto writeV = [&](int pp) {
        *(bf16x8*)&V_lds[pp][(tid >> 2) * 40 + (tid & 3) * 8] = vr0;
        *(bf16x8*)&V_lds[pp][((tid + 256) >> 2) * 40 + (tid & 3) * 8] = vr1;
    };

    loadK(0);
    loadV(0);
    writeK(0);
    writeV(0);
    __syncthreads();

    for (int t = 0; t < TILES; ++t) {
        const int p = t & 1;
        const bool pre = (t + 1 < TILES);
        if (pre) { loadK(t + 1); loadV(t + 1); }   // issue-early

        // ---- S^T = K Q^T : rows = keys, cols = q. s[tt][m2]
        f32x4 s[2][2];
        #pragma unroll
        for (int tt = 0; tt < 2; ++tt)
            #pragma unroll
            for (int m2 = 0; m2 < 2; ++m2) { s[tt][m2][0]=0.f; s[tt][m2][1]=0.f; s[tt][m2][2]=0.f; s[tt][m2][3]=0.f; }
        __builtin_amdgcn_s_setprio(1);
        #pragma unroll
        for (int tt = 0; tt < 2; ++tt) {
            const int row = tt * 16 + lr;
            const int rsw = (row & 7) << 4;
            #pragma unroll
            for (int cf = 0; cf < 4; ++cf) {
                bf16x8 kf = *(const bf16x8*)(&K_lds[p][row * 256 + ((cf * 64 + lg * 16) ^ rsw)]);
                s[tt][0] = mfma16(kf, aq[0][cf], s[tt][0]);
                s[tt][1] = mfma16(kf, aq[1][cf], s[tt][1]);
            }
        }
        __builtin_amdgcn_s_setprio(0);

        // ---- lane-local softmax (base-2, defer-max THR=11)
        float lm[2];
        #pragma unroll
        for (int m2 = 0; m2 < 2; ++m2) {
            float a0 = fmaxf(fmaxf(s[0][m2][0], s[0][m2][1]), fmaxf(s[0][m2][2], s[0][m2][3]));
            float a1 = fmaxf(fmaxf(s[1][m2][0], s[1][m2][1]), fmaxf(s[1][m2][2], s[1][m2][3]));
            lm[m2] = fmaxf(a0, a1);
        }
        int need = (lm[0] > mx[0] + 11.f) || (lm[1] > mx[1] + 11.f);
        if (__any(need)) {
            #pragma unroll
            for (int m2 = 0; m2 < 2; ++m2) {
                float v = lm[m2];
                v = fmaxf(v, __shfl_xor(v, 16));
                v = fmaxf(v, __shfl_xor(v, 32));
                float mn = fmaxf(mx[m2], v);
                float a  = exp2a(mx[m2] - mn);
                mx[m2] = mn;
                l[m2] *= a;
                #pragma unroll
                for (int cc = 0; cc < 8; ++cc) {
                    O[m2][cc][0] *= a; O[m2][cc][1] *= a;
                    O[m2][cc][2] *= a; O[m2][cc][3] *= a;
                }
            }
        }
        // P fragments in-register: slots 0-3 <- tt0 (keys lg*4+r), 4-7 <- tt1
        bf16x8 pb[2];
        #pragma unroll
        for (int m2 = 0; m2 < 2; ++m2) {
            float e[8];
            #pragma unroll
            for (int r = 0; r < 4; ++r) {
                e[r]     = exp2a(s[0][m2][r] - mx[m2]);
                e[4 + r] = exp2a(s[1][m2][r] - mx[m2]);
            }
            l[m2] += ((e[0] + e[1]) + (e[2] + e[3])) + ((e[4] + e[5]) + (e[6] + e[7]));
            union { u32x4 u; bf16x8 b; } cv;
            cv.u[0] = cvtpk(e[0], e[1]);
            cv.u[1] = cvtpk(e[2], e[3]);
            cv.u[2] = cvtpk(e[4], e[5]);
            cv.u[3] = cvtpk(e[6], e[7]);
            pb[m2] = cv.b;
        }

        // ---- O^T += V^T P^T : A = V-frag (same k-permutation), B = P
        __builtin_amdgcn_s_setprio(1);
        #pragma unroll
        for (int cc = 0; cc < 8; ++cc) {
            const short* vb = &V_lds[p][(cc * 16 + lr) * 40 + lg * 4];
            bf16x4 va0 = *(const bf16x4*)vb;         // keys lg*4 + 0..3
            bf16x4 va1 = *(const bf16x4*)(vb + 16);  // keys 16 + lg*4 + 0..3
            bf16x8 vf = __builtin_shufflevector(va0, va1, 0, 1, 2, 3, 4, 5, 6, 7);
            O[0][cc] = mfma16(vf, pb[0], O[0][cc]);
            O[1][cc] = mfma16(vf, pb[1], O[1][cc]);
        }
        __builtin_amdgcn_s_setprio(0);

        if (pre) { writeK(p ^ 1); writeV(p ^ 1); }   // write-late
        __syncthreads();
    }

    // ---- epilogue: reduce l across lg groups, write partial + lse2
    const size_t obase = (size_t)(ks * NB + n) * HW;
    #pragma unroll
    for (int m2 = 0; m2 < 2; ++m2) {
        float v = l[m2];
        v += __shfl_xor(v, 16);
        v += __shfl_xor(v, 32);
        l[m2] = v;
        const float inv = 1.f / v;
        const int q = q0 + m2 * 16 + lr;
        #pragma unroll
        for (int cc = 0; cc < 8; ++cc) {
            uint2 ov;
            ov.x = cvtpk(O[m2][cc][0] * inv, O[m2][cc][1] * inv);
            ov.y = cvtpk(O[m2][cc][2] * inv, O[m2][cc][3] * inv);
            *(uint2*)&Op[(obase + q) * ICH + cc * 16 + lg * 4] = ov;
        }
        if (lg == 0)
            Ls[obase + q] = mx[m2] + log2a(l[m2]);
    }
}

// ---------------------------------------------------------------------------
// K4: fused combine + final conv + residual.
// Phase 1: 256 threads cooperatively combine the 8 k-split partials into an
// XOR-swizzled LDS tile (combine done ONCE, not per-wave). Phase 2: MFMA.
// grid (128, 4) x 256.
// ---------------------------------------------------------------------------
__global__ __launch_bounds__(256) void k_out(const short* __restrict__ Op,
                                             const float* __restrict__ Ls,
                                             const short* __restrict__ wwb,
                                             const float* __restrict__ feat,
                                             float* __restrict__ out) {
    __shared__ char bo_lds[32 * 256];   // 32 q x 128 c bf16, rows 256B, XOR-swizzled
    const int n   = blockIdx.y;
    const int q0  = blockIdx.x * 32;
    const int tid = threadIdx.x;

    // ---- phase 1: combine splits for (q = tid>>3, c = (tid&7)*16 .. +16)
    {
        const int q  = tid >> 3;
        const int c0 = (tid & 7) * 16;
        const int qg = q0 + q;
        float ls[KSPL], M = -INFINITY;
        #pragma unroll
        for (int i = 0; i < KSPL; ++i) {
            ls[i] = Ls[((size_t)(i * NB + n)) * HW + qg];
            M = fmaxf(M, ls[i]);
        }
        float wq[KSPL], ws = 0.f;
        #pragma unroll
        for (int i = 0; i < KSPL; ++i) { wq[i] = exp2a(ls[i] - M); ws += wq[i]; }
        const float inv = 1.f / ws;
        float fo[16];
        #pragma unroll
        for (int e = 0; e < 16; ++e) fo[e] = 0.f;
        #pragma unroll
        for (int i = 0; i < KSPL; ++i) {
            const short* p = Op + ((size_t)(i * NB + n) * HW + qg) * ICH + c0;
            bf16x8 v0 = ldf(p);
            bf16x8 v1 = ldf(p + 8);
            #pragma unroll
            for (int e = 0; e < 8; ++e) {
                fo[e]     += wq[i] * bf2f(v0[e]);
                fo[8 + e] += wq[i] * bf2f(v1[e]);
            }
        }
        const int rsw = (q & 7) << 4;
        u32x4 w0, w1;
        #pragma unroll
        for (int e = 0; e < 4; ++e) {
            w0[e] = cvtpk(fo[2*e] * inv,     fo[2*e+1] * inv);
            w1[e] = cvtpk(fo[8+2*e] * inv,   fo[8+2*e+1] * inv);
        }
        *(u32x4*)&bo_lds[q * 256 + ((c0 * 2) ^ rsw)]        = w0;
        *(u32x4*)&bo_lds[q * 256 + (((c0 + 8) * 2) ^ rsw)]  = w1;
    }
    __syncthreads();

    // ---- phase 2: out[o, q] = ww @ bO + residual
    const int wave = tid >> 6;
    const int lane = tid & 63;
    const int lr = lane & 15, lg = lane >> 4;
    const int o0 = wave * 64;

    f32x4 acc[4][2];
    #pragma unroll
    for (int i = 0; i < 4; ++i)
        #pragma unroll
        for (int jn = 0; jn < 2; ++jn) { acc[i][jn][0]=0.f; acc[i][jn][1]=0.f; acc[i][jn][2]=0.f; acc[i][jn][3]=0.f; }

    #pragma unroll
    for (int cf = 0; cf < 4; ++cf) {
        bf16x8 bO[2];
        #pragma unroll
        for (int nf = 0; nf < 2; ++nf) {
            const int row = nf * 16 + lr;
            const int byt = (cf * 64 + lg * 16) ^ ((row & 7) << 4);
            bO[nf] = *(const bf16x8*)&bo_lds[row * 256 + byt];
        }
        #pragma unroll
        for (int mf = 0; mf < 4; ++mf) {
            bf16x8 a = ldf(wwb + (o0 + mf * 16 + lr) * ICH + cf * 32 + lg * 8);
            #pragma unroll
            for (int nf = 0; nf < 2; ++nf)
                acc[mf][nf] = mfma16(a, bO[nf], acc[mf][nf]);
        }
    }
    #pragma unroll
    for (int mf = 0; mf < 4; ++mf) {
        #pragma unroll
        for (int nf = 0; nf < 2; ++nf) {
            #pragma unroll
            for (int r = 0; r < 4; ++r) {
                int o = o0 + mf * 16 + lg * 4 + r;
                int q = q0 + nf * 16 + lr;
                long long cxi = (((long long)(n * CIN + o)) * 9 + 5) * HW + q;
                out[((long long)(n * CIN + o)) * HW + q] = acc[mf][nf][r] + feat[cxi];
            }
        }
    }
}

// ---------------------------------------------------------------------------
extern "C" void kernel_launch(void* const* d_in, const int* in_sizes, int n_in,
                              void* d_out, int out_size, void* d_ws, size_t ws_size,
                              hipStream_t stream) {
    const float* feat = (const float*)d_in[0];
    const float* wth  = (const float*)d_in[1];
    const float* gth  = (const float*)d_in[2];
    const float* bth  = (const float*)d_in[3];
    const float* mth  = (const float*)d_in[4];
    const float* vth  = (const float*)d_in[5];
    const float* wph  = (const float*)d_in[6];
    const float* gph  = (const float*)d_in[7];
    const float* bph  = (const float*)d_in[8];
    const float* mph  = (const float*)d_in[9];
    const float* vph  = (const float*)d_in[10];
    const float* wg   = (const float*)d_in[11];
    const float* ww   = (const float*)d_in[12];
    float* out = (float*)d_out;

    size_t off = 0;
    auto carve = [&](size_t bytes) {
        void* p = (char*)d_ws + off;
        off += (bytes + 255) & ~(size_t)255;
        return p;
    };
    short* Xbf   = (short*)carve((size_t)NB * HW * CIN * 2);
    short* CXbf  = (short*)carve((size_t)NB * HW * CIN * 2);
    short* theta = (short*)carve((size_t)NB * HW * ICH * 2);
    short* phi   = (short*)carve((size_t)NB * HW * ICH * 2);
    short* Vt    = (short*)carve((size_t)NB * ICH * HW * 2);
    short* Op    = (short*)carve((size_t)KSPL * NB * HW * ICH * 2);
    float* Ls    = (float*)carve((size_t)KSPL * NB * HW * 4);
    short* wthb  = (short*)carve((size_t)ICH * CIN * 2);
    short* wphb  = (short*)carve((size_t)ICH * CIN * 2);
    short* wgb   = (short*)carve((size_t)ICH * CIN * 2);
    short* wwb   = (short*)carve((size_t)CIN * ICH * 2);
    float* bnp   = (float*)carve((size_t)4 * ICH * 4);

    k_prep_w<<<128, 256, 0, stream>>>(wth, wph, wg, ww, gth, bth, mth, vth,
                                      gph, bph, mph, vph, wthb, wphb, wgb, wwb, bnp);
    k_prep_x<<<dim3(64, 8, NB), 256, 0, stream>>>(feat, Xbf, CXbf);
    k_conv3<<<dim3(64, NB), 256, 0, stream>>>(Xbf, CXbf, wthb, wphb, wgb, bnp,
                                              theta, phi, Vt);
    k_attn<<<1024, 256, 0, stream>>>(theta, phi, Vt, Op, Ls);
    k_out<<<dim3(128, NB), 256, 0, stream>>>(Op, Ls, wwb, feat, out);
}

// Round 8
// 119.825 us; speedup vs baseline: 2.3482x; 1.2250x over previous
//
#include <hip/hip_runtime.h>
#include <math.h>

#define HW   4096
#define CIN  256
#define ICH  128
#define NB   4
#define KSPL 6      // 6 uneven k-splits: grid 32*6*4 = 768 = 3 blocks/CU exactly
#define KVB  32

typedef __attribute__((ext_vector_type(4))) float f32x4;
typedef __attribute__((ext_vector_type(8))) short bf16x8;
typedef __attribute__((ext_vector_type(4))) short bf16x4;
typedef __attribute__((ext_vector_type(4))) unsigned u32x4;

__device__ inline short f2bf(float f) {
    unsigned int u = __float_as_uint(f);
    u += 0x7fffU + ((u >> 16) & 1U);   // round-to-nearest-even
    return (short)(u >> 16);
}

__device__ inline float bf2f(short s) {
    return __uint_as_float(((unsigned int)(unsigned short)s) << 16);
}

__device__ inline float exp2a(float x) {  // 2^x, handles -inf -> 0
    float r;
    asm("v_exp_f32 %0, %1" : "=v"(r) : "v"(x));
    return r;
}
__device__ inline float log2a(float x) {
    float r;
    asm("v_log_f32 %0, %1" : "=v"(r) : "v"(x));
    return r;
}
__device__ inline unsigned cvtpk(float a, float b) {  // lo=bf16(a), hi=bf16(b), RNE
    unsigned r;
    asm("v_cvt_pk_bf16_f32 %0, %1, %2" : "=v"(r) : "v"(a), "v"(b));
    return r;
}

__device__ inline f32x4 mfma16(bf16x8 a, bf16x8 b, f32x4 c) {
    return __builtin_amdgcn_mfma_f32_16x16x32_bf16(a, b, c, 0, 0, 0);
}

__device__ inline bf16x8 ldf(const short* p) { return *(const bf16x8*)p; }

// ---------------------------------------------------------------------------
// K0: weights -> bf16; fold BN params. Theta's BN scale/bias folded with
// log2(e) so attention logits are base-2.
// ---------------------------------------------------------------------------
__global__ void k_prep_w(const float* __restrict__ wth, const float* __restrict__ wph,
                         const float* __restrict__ wg,  const float* __restrict__ ww,
                         const float* __restrict__ gth, const float* __restrict__ bth,
                         const float* __restrict__ mth, const float* __restrict__ vth,
                         const float* __restrict__ gph, const float* __restrict__ bph,
                         const float* __restrict__ mph, const float* __restrict__ vph,
                         short* __restrict__ wthb, short* __restrict__ wphb,
                         short* __restrict__ wgb,  short* __restrict__ wwb,
                         float* __restrict__ bnp) {
    const float LOG2E = 1.44269504f;
    int i = blockIdx.x * 256 + threadIdx.x;
    wthb[i] = f2bf(wth[i]);
    wphb[i] = f2bf(wph[i]);
    wgb[i]  = f2bf(wg[i]);
    wwb[i]  = f2bf(ww[i]);
    if (blockIdx.x == 0 && threadIdx.x < ICH) {
        int o = threadIdx.x;
        float s1 = gth[o] * rsqrtf(vth[o] + 1e-5f);
        bnp[o]        = s1 * LOG2E;
        bnp[ICH + o]  = (bth[o] - mth[o] * s1) * LOG2E;
        float s2 = gph[o] * rsqrtf(vph[o] + 1e-5f);
        bnp[2*ICH + o] = s2;
        bnp[3*ICH + o] = bph[o] - mph[o] * s2;
    }
}

// ---------------------------------------------------------------------------
// K1: x = max_d(feature), cx = feature[:, :, 5]; write (n,q,c) bf16.
// ---------------------------------------------------------------------------
__global__ __launch_bounds__(256) void k_prep_x(const float* __restrict__ feat,
                                                short* __restrict__ Xbf,
                                                short* __restrict__ CXbf) {
    const int q0 = blockIdx.x * 64;
    const int c0 = blockIdx.y * 32;
    const int n  = blockIdx.z;
    __shared__ float xs[32][68];
    __shared__ float cxs[32][68];
    const int tid = threadIdx.x;
    const int qv  = (tid & 15) * 4;
    const int ci  = tid >> 4;          // 0..15

    #pragma unroll
    for (int h = 0; h < 2; ++h) {
        const int cc = h * 16 + ci;
        const float* fp = feat + ((size_t)(n * CIN + c0 + cc)) * 9 * HW + q0 + qv;
        float4 mx = *(const float4*)fp;
        float4 cx = make_float4(0.f, 0.f, 0.f, 0.f);
        #pragma unroll
        for (int d = 1; d < 9; ++d) {
            float4 v = *(const float4*)(fp + (size_t)d * HW);
            if (d == 5) cx = v;
            mx.x = fmaxf(mx.x, v.x); mx.y = fmaxf(mx.y, v.y);
            mx.z = fmaxf(mx.z, v.z); mx.w = fmaxf(mx.w, v.w);
        }
        *(float4*)&xs[cc][qv]  = mx;
        *(float4*)&cxs[cc][qv] = cx;
    }
    __syncthreads();
    #pragma unroll
    for (int it = 0; it < 2; ++it) {
        const int q  = it * 32 + (tid >> 3);
        const int cq = (tid & 7) * 4;
        ushort4 ox, oc;
        ox.x = (unsigned short)f2bf(xs[cq][q]);
        ox.y = (unsigned short)f2bf(xs[cq + 1][q]);
        ox.z = (unsigned short)f2bf(xs[cq + 2][q]);
        ox.w = (unsigned short)f2bf(xs[cq + 3][q]);
        oc.x = (unsigned short)f2bf(cxs[cq][q]);
        oc.y = (unsigned short)f2bf(cxs[cq + 1][q]);
        oc.z = (unsigned short)f2bf(cxs[cq + 2][q]);
        oc.w = (unsigned short)f2bf(cxs[cq + 3][q]);
        const size_t ob = ((size_t)n * HW + q0 + q) * CIN + c0 + cq;
        *(ushort4*)&Xbf[ob]  = ox;
        *(ushort4*)&CXbf[ob] = oc;
    }
}

// ---------------------------------------------------------------------------
// K2: one of {theta, phi, g} per blockIdx.z -> grid (64, 4, 3) = 768 blocks
// (3 blocks/CU vs 1 before; the three GEMMs are independent).
// theta/phi (q,c) with BN+ReLU; g with swapped roles -> Vt (c,k).
// ---------------------------------------------------------------------------
__global__ __launch_bounds__(256) void k_conv3(const short* __restrict__ Xbf,
                                               const short* __restrict__ CXbf,
                                               const short* __restrict__ wthb,
                                               const short* __restrict__ wphb,
                                               const short* __restrict__ wgb,
                                               const float* __restrict__ bnp,
                                               short* __restrict__ theta,
                                               short* __restrict__ phi,
                                               short* __restrict__ Vt) {
    const int n    = blockIdx.y;
    const int op   = blockIdx.z;
    const int wave = threadIdx.x >> 6;
    const int lane = threadIdx.x & 63;
    const int lr = lane & 15, lg = lane >> 4;
    const int q0 = blockIdx.x * 64 + wave * 16;
    const short* Xn  = Xbf  + (size_t)n * HW * CIN;
    const short* CXn = CXbf + (size_t)n * HW * CIN;

    f32x4 acc[8];
    #pragma unroll
    for (int i = 0; i < 8; ++i) { acc[i][0]=0.f; acc[i][1]=0.f; acc[i][2]=0.f; acc[i][3]=0.f; }

    if (op == 0) {          // theta = relu(bn(Wth @ cx))
        short* thn = theta + (size_t)n * HW * ICH;
        #pragma unroll
        for (int cf = 0; cf < 8; ++cf) {
            bf16x8 a = ldf(CXn + (q0 + lr) * CIN + cf * 32 + lg * 8);
            #pragma unroll
            for (int of = 0; of < 8; ++of) {
                bf16x8 b = ldf(wthb + (of * 16 + lr) * CIN + cf * 32 + lg * 8);
                acc[of] = mfma16(a, b, acc[of]);
            }
        }
        #pragma unroll
        for (int of = 0; of < 8; ++of) {
            int o = of * 16 + lr;
            float sA = bnp[o], sB = bnp[ICH + o];
            #pragma unroll
            for (int r = 0; r < 4; ++r) {
                int q = q0 + lg * 4 + r;
                thn[q * ICH + o] = f2bf(fmaxf(acc[of][r] * sA + sB, 0.f));
            }
        }
    } else if (op == 1) {   // phi = relu(bn(Wph @ x))
        short* phn = phi + (size_t)n * HW * ICH;
        #pragma unroll
        for (int cf = 0; cf < 8; ++cf) {
            bf16x8 a = ldf(Xn + (q0 + lr) * CIN + cf * 32 + lg * 8);
            #pragma unroll
            for (int of = 0; of < 8; ++of) {
                bf16x8 b = ldf(wphb + (of * 16 + lr) * CIN + cf * 32 + lg * 8);
                acc[of] = mfma16(a, b, acc[of]);
            }
        }
        #pragma unroll
        for (int of = 0; of < 8; ++of) {
            int o = of * 16 + lr;
            float sA = bnp[2*ICH + o], sB = bnp[3*ICH + o];
            #pragma unroll
            for (int r = 0; r < 4; ++r) {
                int q = q0 + lg * 4 + r;
                phn[q * ICH + o] = f2bf(fmaxf(acc[of][r] * sA + sB, 0.f));
            }
        }
    } else {                // g = Wg @ x, swapped MFMA roles -> Vt (c,k)
        short* vtn = Vt + (size_t)n * ICH * HW;
        #pragma unroll
        for (int cf = 0; cf < 8; ++cf) {
            bf16x8 bx = ldf(Xn + (q0 + lr) * CIN + cf * 32 + lg * 8);
            #pragma unroll
            for (int mf = 0; mf < 8; ++mf) {
                bf16x8 a = ldf(wgb + (mf * 16 + lr) * CIN + cf * 32 + lg * 8);
                acc[mf] = mfma16(a, bx, acc[mf]);
            }
        }
        #pragma unroll
        for (int mf = 0; mf < 8; ++mf) {
            #pragma unroll
            for (int r = 0; r < 4; ++r) {
                int o = mf * 16 + lg * 4 + r;
                vtn[(size_t)o * HW + q0 + lr] = f2bf(acc[mf][r]);
            }
        }
    }
}

// ---------------------------------------------------------------------------
// K3: flash attention, k-split x6 (uneven 22/22/21/21/21/21 tiles), swapped
// QK^T -> lane-local softmax + in-register P. K and V reg-staged (T14
// issue-early/write-late), K LDS XOR-swizzled, V 80B-stride. One barrier/tile.
// grid 768 x 256 = 3 blocks/CU EXACTLY (no occupancy tail).
// XCD mapping: n = (bid&7)>>1.
// ---------------------------------------------------------------------------
__global__ __launch_bounds__(256, 3) void k_attn(const short* __restrict__ theta,
                                                 const short* __restrict__ phi,
                                                 const short* __restrict__ Vt,
                                                 short* __restrict__ Op,
                                                 float* __restrict__ Ls) {
    __shared__ char  K_lds[2][8192];        // 32 keys x 128 ch bf16, XOR-swizzled
    __shared__ short V_lds[2][128 * 40];    // 128 ch x 32 keys, stride 40 shorts

    const int bid  = blockIdx.x;
    const int j    = bid & 7;
    const int n    = j >> 1;
    const int rest = ((bid >> 3) << 1) | (j & 1);   // 0..191
    const int qb   = rest / KSPL;                   // 0..31
    const int ks   = rest % KSPL;                   // 0..5
    const int tbase = ks * 21 + (ks < 2 ? ks : 2);  // 0,22,44,65,86,107
    const int tcnt  = 21 + (ks < 2 ? 1 : 0);
    const int tid  = threadIdx.x;
    const int wave = tid >> 6;
    const int lane = tid & 63;
    const int lr = lane & 15, lg = lane >> 4;
    const int q0 = qb * 128 + wave * 32;

    const short* Qn = theta + (size_t)n * HW * ICH;
    const short* Kn = phi   + (size_t)n * HW * ICH;
    const short* Vn = Vt    + (size_t)n * ICH * HW;

    bf16x8 aq[2][4];
    #pragma unroll
    for (int m2 = 0; m2 < 2; ++m2)
        #pragma unroll
        for (int cf = 0; cf < 4; ++cf)
            aq[m2][cf] = ldf(Qn + (q0 + m2 * 16 + lr) * ICH + cf * 32 + lg * 8);

    // O^T accumulators: O[m2][cc] rows c = cc*16+lg*4+r, col q = q0+m2*16+lr
    f32x4 O[2][8];
    #pragma unroll
    for (int m2 = 0; m2 < 2; ++m2)
        #pragma unroll
        for (int i = 0; i < 8; ++i) { O[m2][i][0]=0.f; O[m2][i][1]=0.f; O[m2][i][2]=0.f; O[m2][i][3]=0.f; }
    float mx[2] = { -INFINITY, -INFINITY };
    float l[2]  = { 0.f, 0.f };

    bf16x8 kr0, kr1, vr0, vr1;
    auto loadK = [&](int tabs) {   // linear coalesced b128; swizzle applied on WRITE
        const char* kc = (const char*)(Kn + (size_t)tabs * KVB * ICH);
        kr0 = *(const bf16x8*)(kc + tid * 16);
        kr1 = *(const bf16x8*)(kc + 4096 + tid * 16);
    };
    auto writeK = [&](int pp) {
        const int o0 = tid * 16;
        const int o1 = 4096 + tid * 16;
        *(bf16x8*)&K_lds[pp][o0 ^ (((o0 >> 8) & 7) << 4)] = kr0;
        *(bf16x8*)&K_lds[pp][o1 ^ (((o1 >> 8) & 7) << 4)] = kr1;
    };
    auto loadV = [&](int tabs) {
        vr0 = ldf(Vn + (size_t)(tid >> 2) * HW + tabs * KVB + (tid & 3) * 8);
        vr1 = ldf(Vn + (size_t)((tid + 256) >> 2) * HW + tabs * KVB + (tid & 3) * 8);
    };
    auto writeV = [&](int pp) {
        *(bf16x8*)&V_lds[pp][(tid >> 2) * 40 + (tid & 3) * 8] = vr0;
        *(bf16x8*)&V_lds[pp][((tid + 256) >> 2) * 40 + (tid & 3) * 8] = vr1;
    };

    loadK(tbase);
    loadV(tbase);
    writeK(0);
    writeV(0);
    __syncthreads();

    for (int t = 0; t < tcnt; ++t) {
        const int p = t & 1;
        const bool pre = (t + 1 < tcnt);
        if (pre) { loadK(tbase + t + 1); loadV(tbase + t + 1); }   // issue-early

        // ---- S^T = K Q^T : rows = keys, cols = q. s[tt][m2]
        f32x4 s[2][2];
        #pragma unroll
        for (int tt = 0; tt < 2; ++tt)
            #pragma unroll
            for (int m2 = 0; m2 < 2; ++m2) { s[tt][m2][0]=0.f; s[tt][m2][1]=0.f; s[tt][m2][2]=0.f; s[tt][m2][3]=0.f; }
        __builtin_amdgcn_s_setprio(1);
        #pragma unroll
        for (int tt = 0; tt < 2; ++tt) {
            const int row = tt * 16 + lr;
            const int rsw = (row & 7) << 4;
            #pragma unroll
            for (int cf = 0; cf < 4; ++cf) {
                bf16x8 kf = *(const bf16x8*)(&K_lds[p][row * 256 + ((cf * 64 + lg * 16) ^ rsw)]);
                s[tt][0] = mfma16(kf, aq[0][cf], s[tt][0]);
                s[tt][1] = mfma16(kf, aq[1][cf], s[tt][1]);
            }
        }
        __builtin_amdgcn_s_setprio(0);

        // ---- lane-local softmax (base-2, defer-max THR=11)
        float lm[2];
        #pragma unroll
        for (int m2 = 0; m2 < 2; ++m2) {
            float a0 = fmaxf(fmaxf(s[0][m2][0], s[0][m2][1]), fmaxf(s[0][m2][2], s[0][m2][3]));
            float a1 = fmaxf(fmaxf(s[1][m2][0], s[1][m2][1]), fmaxf(s[1][m2][2], s[1][m2][3]));
            lm[m2] = fmaxf(a0, a1);
        }
        int need = (lm[0] > mx[0] + 11.f) || (lm[1] > mx[1] + 11.f);
        if (__any(need)) {
            #pragma unroll
            for (int m2 = 0; m2 < 2; ++m2) {
                float v = lm[m2];
                v = fmaxf(v, __shfl_xor(v, 16));
                v = fmaxf(v, __shfl_xor(v, 32));
                float mn = fmaxf(mx[m2], v);
                float a  = exp2a(mx[m2] - mn);
                mx[m2] = mn;
                l[m2] *= a;
                #pragma unroll
                for (int cc = 0; cc < 8; ++cc) {
                    O[m2][cc][0] *= a; O[m2][cc][1] *= a;
                    O[m2][cc][2] *= a; O[m2][cc][3] *= a;
                }
            }
        }
        // P fragments in-register: slots 0-3 <- tt0 (keys lg*4+r), 4-7 <- tt1
        bf16x8 pb[2];
        #pragma unroll
        for (int m2 = 0; m2 < 2; ++m2) {
            float e[8];
            #pragma unroll
            for (int r = 0; r < 4; ++r) {
                e[r]     = exp2a(s[0][m2][r] - mx[m2]);
                e[4 + r] = exp2a(s[1][m2][r] - mx[m2]);
            }
            l[m2] += ((e[0] + e[1]) + (e[2] + e[3])) + ((e[4] + e[5]) + (e[6] + e[7]));
            union { u32x4 u; bf16x8 b; } cv;
            cv.u[0] = cvtpk(e[0], e[1]);
            cv.u[1] = cvtpk(e[2], e[3]);
            cv.u[2] = cvtpk(e[4], e[5]);
            cv.u[3] = cvtpk(e[6], e[7]);
            pb[m2] = cv.b;
        }

        // ---- O^T += V^T P^T : A = V-frag (same k-permutation), B = P
        __builtin_amdgcn_s_setprio(1);
        #pragma unroll
        for (int cc = 0; cc < 8; ++cc) {
            const short* vb = &V_lds[p][(cc * 16 + lr) * 40 + lg * 4];
            bf16x4 va0 = *(const bf16x4*)vb;         // keys lg*4 + 0..3
            bf16x4 va1 = *(const bf16x4*)(vb + 16);  // keys 16 + lg*4 + 0..3
            bf16x8 vf = __builtin_shufflevector(va0, va1, 0, 1, 2, 3, 4, 5, 6, 7);
            O[0][cc] = mfma16(vf, pb[0], O[0][cc]);
            O[1][cc] = mfma16(vf, pb[1], O[1][cc]);
        }
        __builtin_amdgcn_s_setprio(0);

        if (pre) { writeK(p ^ 1); writeV(p ^ 1); }   // write-late
        __syncthreads();
    }

    // ---- epilogue: reduce l across lg groups, write partial + lse2
    const size_t obase = (size_t)(ks * NB + n) * HW;
    #pragma unroll
    for (int m2 = 0; m2 < 2; ++m2) {
        float v = l[m2];
        v += __shfl_xor(v, 16);
        v += __shfl_xor(v, 32);
        l[m2] = v;
        const float inv = 1.f / v;
        const int q = q0 + m2 * 16 + lr;
        #pragma unroll
        for (int cc = 0; cc < 8; ++cc) {
            uint2 ov;
            ov.x = cvtpk(O[m2][cc][0] * inv, O[m2][cc][1] * inv);
            ov.y = cvtpk(O[m2][cc][2] * inv, O[m2][cc][3] * inv);
            *(uint2*)&Op[(obase + q) * ICH + cc * 16 + lg * 4] = ov;
        }
        if (lg == 0)
            Ls[obase + q] = mx[m2] + log2a(l[m2]);
    }
}

// ---------------------------------------------------------------------------
// K4: fused combine + final conv + residual.
// Phase 1: 256 threads cooperatively combine the 6 k-split partials into an
// XOR-swizzled LDS tile. Phase 2: MFMA. grid (128, 4) x 256.
// ---------------------------------------------------------------------------
__global__ __launch_bounds__(256) void k_out(const short* __restrict__ Op,
                                             const float* __restrict__ Ls,
                                             const short* __restrict__ wwb,
                                             const float* __restrict__ feat,
                                             float* __restrict__ out) {
    __shared__ char bo_lds[32 * 256];   // 32 q x 128 c bf16, rows 256B, XOR-swizzled
    const int n   = blockIdx.y;
    const int q0  = blockIdx.x * 32;
    const int tid = threadIdx.x;

    // ---- phase 1: combine splits for (q = tid>>3, c = (tid&7)*16 .. +16)
    {
        const int q  = tid >> 3;
        const int c0 = (tid & 7) * 16;
        const int qg = q0 + q;
        float ls[KSPL], M = -INFINITY;
        #pragma unroll
        for (int i = 0; i < KSPL; ++i) {
            ls[i] = Ls[((size_t)(i * NB + n)) * HW + qg];
            M = fmaxf(M, ls[i]);
        }
        float wq[KSPL], ws = 0.f;
        #pragma unroll
        for (int i = 0; i < KSPL; ++i) { wq[i] = exp2a(ls[i] - M); ws += wq[i]; }
        const float inv = 1.f / ws;
        float fo[16];
        #pragma unroll
        for (int e = 0; e < 16; ++e) fo[e] = 0.f;
        #pragma unroll
        for (int i = 0; i < KSPL; ++i) {
            const short* p = Op + ((size_t)(i * NB + n) * HW + qg) * ICH + c0;
            bf16x8 v0 = ldf(p);
            bf16x8 v1 = ldf(p + 8);
            #pragma unroll
            for (int e = 0; e < 8; ++e) {
                fo[e]     += wq[i] * bf2f(v0[e]);
                fo[8 + e] += wq[i] * bf2f(v1[e]);
            }
        }
        const int rsw = (q & 7) << 4;
        u32x4 w0, w1;
        #pragma unroll
        for (int e = 0; e < 4; ++e) {
            w0[e] = cvtpk(fo[2*e] * inv,     fo[2*e+1] * inv);
            w1[e] = cvtpk(fo[8+2*e] * inv,   fo[8+2*e+1] * inv);
        }
        *(u32x4*)&bo_lds[q * 256 + ((c0 * 2) ^ rsw)]        = w0;
        *(u32x4*)&bo_lds[q * 256 + (((c0 + 8) * 2) ^ rsw)]  = w1;
    }
    __syncthreads();

    // ---- phase 2: out[o, q] = ww @ bO + residual
    const int wave = tid >> 6;
    const int lane = tid & 63;
    const int lr = lane & 15, lg = lane >> 4;
    const int o0 = wave * 64;

    f32x4 acc[4][2];
    #pragma unroll
    for (int i = 0; i < 4; ++i)
        #pragma unroll
        for (int jn = 0; jn < 2; ++jn) { acc[i][jn][0]=0.f; acc[i][jn][1]=0.f; acc[i][jn][2]=0.f; acc[i][jn][3]=0.f; }

    #pragma unroll
    for (int cf = 0; cf < 4; ++cf) {
        bf16x8 bO[2];
        #pragma unroll
        for (int nf = 0; nf < 2; ++nf) {
            const int row = nf * 16 + lr;
            const int byt = (cf * 64 + lg * 16) ^ ((row & 7) << 4);
            bO[nf] = *(const bf16x8*)&bo_lds[row * 256 + byt];
        }
        #pragma unroll
        for (int mf = 0; mf < 4; ++mf) {
            bf16x8 a = ldf(wwb + (o0 + mf * 16 + lr) * ICH + cf * 32 + lg * 8);
            #pragma unroll
            for (int nf = 0; nf < 2; ++nf)
                acc[mf][nf] = mfma16(a, bO[nf], acc[mf][nf]);
        }
    }
    #pragma unroll
    for (int mf = 0; mf < 4; ++mf) {
        #pragma unroll
        for (int nf = 0; nf < 2; ++nf) {
            #pragma unroll
            for (int r = 0; r < 4; ++r) {
                int o = o0 + mf * 16 + lg * 4 + r;
                int q = q0 + nf * 16 + lr;
                long long cxi = (((long long)(n * CIN + o)) * 9 + 5) * HW + q;
                out[((long long)(n * CIN + o)) * HW + q] = acc[mf][nf][r] + feat[cxi];
            }
        }
    }
}

// ---------------------------------------------------------------------------
extern "C" void kernel_launch(void* const* d_in, const int* in_sizes, int n_in,
                              void* d_out, int out_size, void* d_ws, size_t ws_size,
                              hipStream_t stream) {
    const float* feat = (const float*)d_in[0];
    const float* wth  = (const float*)d_in[1];
    const float* gth  = (const float*)d_in[2];
    const float* bth  = (const float*)d_in[3];
    const float* mth  = (const float*)d_in[4];
    const float* vth  = (const float*)d_in[5];
    const float* wph  = (const float*)d_in[6];
    const float* gph  = (const float*)d_in[7];
    const float* bph  = (const float*)d_in[8];
    const float* mph  = (const float*)d_in[9];
    const float* vph  = (const float*)d_in[10];
    const float* wg   = (const float*)d_in[11];
    const float* ww   = (const float*)d_in[12];
    float* out = (float*)d_out;

    size_t off = 0;
    auto carve = [&](size_t bytes) {
        void* p = (char*)d_ws + off;
        off += (bytes + 255) & ~(size_t)255;
        return p;
    };
    short* Xbf   = (short*)carve((size_t)NB * HW * CIN * 2);
    short* CXbf  = (short*)carve((size_t)NB * HW * CIN * 2);
    short* theta = (short*)carve((size_t)NB * HW * ICH * 2);
    short* phi   = (short*)carve((size_t)NB * HW * ICH * 2);
    short* Vt    = (short*)carve((size_t)NB * ICH * HW * 2);
    short* Op    = (short*)carve((size_t)KSPL * NB * HW * ICH * 2);
    float* Ls    = (float*)carve((size_t)KSPL * NB * HW * 4);
    short* wthb  = (short*)carve((size_t)ICH * CIN * 2);
    short* wphb  = (short*)carve((size_t)ICH * CIN * 2);
    short* wgb   = (short*)carve((size_t)ICH * CIN * 2);
    short* wwb   = (short*)carve((size_t)CIN * ICH * 2);
    float* bnp   = (float*)carve((size_t)4 * ICH * 4);

    k_prep_w<<<128, 256, 0, stream>>>(wth, wph, wg, ww, gth, bth, mth, vth,
                                      gph, bph, mph, vph, wthb, wphb, wgb, wwb, bnp);
    k_prep_x<<<dim3(64, 8, NB), 256, 0, stream>>>(feat, Xbf, CXbf);
    k_conv3<<<dim3(64, NB, 3), 256, 0, stream>>>(Xbf, CXbf, wthb, wphb, wgb, bnp,
                                                 theta, phi, Vt);
    k_attn<<<768, 256, 0, stream>>>(theta, phi, Vt, Op, Ls);
    k_out<<<dim3(128, NB), 256, 0, stream>>>(Op, Ls, wwb, feat, out);
}

// Round 10
// 114.576 us; speedup vs baseline: 2.4558x; 1.0458x over previous
//
#include <hip/hip_runtime.h>
#include <math.h>

#define HW   4096
#define CIN  256
#define ICH  128
#define NB   4
#define KSPL 6      // 6 uneven k-splits: grid 32*6*4 = 768 = 3 blocks/CU exactly
#define KVB  32

typedef __attribute__((ext_vector_type(4))) float f32x4;
typedef __attribute__((ext_vector_type(8))) short bf16x8;
typedef __attribute__((ext_vector_type(4))) short bf16x4;
typedef __attribute__((ext_vector_type(4))) unsigned u32x4;

__device__ inline short f2bf(float f) {
    unsigned int u = __float_as_uint(f);
    u += 0x7fffU + ((u >> 16) & 1U);   // round-to-nearest-even
    return (short)(u >> 16);
}

__device__ inline float bf2f(short s) {
    return __uint_as_float(((unsigned int)(unsigned short)s) << 16);
}

__device__ inline float exp2a(float x) {  // 2^x, handles -inf -> 0
    float r;
    asm("v_exp_f32 %0, %1" : "=v"(r) : "v"(x));
    return r;
}
__device__ inline float log2a(float x) {
    float r;
    asm("v_log_f32 %0, %1" : "=v"(r) : "v"(x));
    return r;
}
__device__ inline unsigned cvtpk(float a, float b) {  // lo=bf16(a), hi=bf16(b), RNE
    unsigned r;
    asm("v_cvt_pk_bf16_f32 %0, %1, %2" : "=v"(r) : "v"(a), "v"(b));
    return r;
}

__device__ inline f32x4 mfma16(bf16x8 a, bf16x8 b, f32x4 c) {
    return __builtin_amdgcn_mfma_f32_16x16x32_bf16(a, b, c, 0, 0, 0);
}

__device__ inline bf16x8 ldf(const short* p) { return *(const bf16x8*)p; }

// ---------------------------------------------------------------------------
// K1: x = max_d(feature), cx = feature[:, :, 5]; write (n,q,c) bf16.
// Blocks with blockIdx.y==0 additionally convert the 4 weight matrices to
// bf16 and (block 0) fold the BN params (k_prep_w fused away).
// ---------------------------------------------------------------------------
__global__ __launch_bounds__(256) void k_prep_x(const float* __restrict__ feat,
                                                short* __restrict__ Xbf,
                                                short* __restrict__ CXbf,
                                                const float* __restrict__ wth,
                                                const float* __restrict__ wph,
                                                const float* __restrict__ wg,
                                                const float* __restrict__ ww,
                                                const float* __restrict__ gth,
                                                const float* __restrict__ bth,
                                                const float* __restrict__ mth,
                                                const float* __restrict__ vth,
                                                const float* __restrict__ gph,
                                                const float* __restrict__ bph,
                                                const float* __restrict__ mph,
                                                const float* __restrict__ vph,
                                                short* __restrict__ wthb,
                                                short* __restrict__ wphb,
                                                short* __restrict__ wgb,
                                                short* __restrict__ wwb,
                                                float* __restrict__ bnp) {
    const float LOG2E = 1.44269504f;
    const int q0 = blockIdx.x * 64;
    const int c0 = blockIdx.y * 32;
    const int n  = blockIdx.z;
    __shared__ float xs[32][68];
    __shared__ float cxs[32][68];
    const int tid = threadIdx.x;

    // ---- fused weight prep (256 blocks with y==0; 128 elems/matrix each)
    if (blockIdx.y == 0) {
        const int wid = blockIdx.x + 64 * n;       // 0..255
        const int i = wid * 128 + (tid & 127);
        if (tid < 128) {
            wthb[i] = f2bf(wth[i]);
            wphb[i] = f2bf(wph[i]);
        } else {
            wgb[i] = f2bf(wg[i]);
            wwb[i] = f2bf(ww[i]);
        }
        if (wid == 0 && tid < ICH) {
            int o = tid;
            float s1 = gth[o] * rsqrtf(vth[o] + 1e-5f);
            bnp[o]        = s1 * LOG2E;
            bnp[ICH + o]  = (bth[o] - mth[o] * s1) * LOG2E;
            float s2 = gph[o] * rsqrtf(vph[o] + 1e-5f);
            bnp[2*ICH + o] = s2;
            bnp[3*ICH + o] = bph[o] - mph[o] * s2;
        }
    }

    const int qv  = (tid & 15) * 4;
    const int ci  = tid >> 4;          // 0..15

    #pragma unroll
    for (int h = 0; h < 2; ++h) {
        const int cc = h * 16 + ci;
        const float* fp = feat + ((size_t)(n * CIN + c0 + cc)) * 9 * HW + q0 + qv;
        float4 mx = *(const float4*)fp;
        float4 cx = make_float4(0.f, 0.f, 0.f, 0.f);
        #pragma unroll
        for (int d = 1; d < 9; ++d) {
            float4 v = *(const float4*)(fp + (size_t)d * HW);
            if (d == 5) cx = v;
            mx.x = fmaxf(mx.x, v.x); mx.y = fmaxf(mx.y, v.y);
            mx.z = fmaxf(mx.z, v.z); mx.w = fmaxf(mx.w, v.w);
        }
        *(float4*)&xs[cc][qv]  = mx;
        *(float4*)&cxs[cc][qv] = cx;
    }
    __syncthreads();
    #pragma unroll
    for (int it = 0; it < 2; ++it) {
        const int q  = it * 32 + (tid >> 3);
        const int cq = (tid & 7) * 4;
        ushort4 ox, oc;
        ox.x = (unsigned short)f2bf(xs[cq][q]);
        ox.y = (unsigned short)f2bf(xs[cq + 1][q]);
        ox.z = (unsigned short)f2bf(xs[cq + 2][q]);
        ox.w = (unsigned short)f2bf(xs[cq + 3][q]);
        oc.x = (unsigned short)f2bf(cxs[cq][q]);
        oc.y = (unsigned short)f2bf(cxs[cq + 1][q]);
        oc.z = (unsigned short)f2bf(cxs[cq + 2][q]);
        oc.w = (unsigned short)f2bf(cxs[cq + 3][q]);
        const size_t ob = ((size_t)n * HW + q0 + q) * CIN + c0 + cq;
        *(ushort4*)&Xbf[ob]  = ox;
        *(ushort4*)&CXbf[ob] = oc;
    }
}

// ---------------------------------------------------------------------------
// K2: one of {theta, phi, g} per blockIdx.z -> grid (64, 4, 3) = 768 blocks.
// theta/phi (q,c) with BN+ReLU; g with swapped roles -> Vt (c,k).
// ---------------------------------------------------------------------------
__global__ __launch_bounds__(256) void k_conv3(const short* __restrict__ Xbf,
                                               const short* __restrict__ CXbf,
                                               const short* __restrict__ wthb,
                                               const short* __restrict__ wphb,
                                               const short* __restrict__ wgb,
                                               const float* __restrict__ bnp,
                                               short* __restrict__ theta,
                                               short* __restrict__ phi,
                                               short* __restrict__ Vt) {
    const int n    = blockIdx.y;
    const int op   = blockIdx.z;
    const int wave = threadIdx.x >> 6;
    const int lane = threadIdx.x & 63;
    const int lr = lane & 15, lg = lane >> 4;
    const int q0 = blockIdx.x * 64 + wave * 16;
    const short* Xn  = Xbf  + (size_t)n * HW * CIN;
    const short* CXn = CXbf + (size_t)n * HW * CIN;

    f32x4 acc[8];
    #pragma unroll
    for (int i = 0; i < 8; ++i) { acc[i][0]=0.f; acc[i][1]=0.f; acc[i][2]=0.f; acc[i][3]=0.f; }

    if (op == 0) {          // theta = relu(bn(Wth @ cx))
        short* thn = theta + (size_t)n * HW * ICH;
        #pragma unroll
        for (int cf = 0; cf < 8; ++cf) {
            bf16x8 a = ldf(CXn + (q0 + lr) * CIN + cf * 32 + lg * 8);
            #pragma unroll
            for (int of = 0; of < 8; ++of) {
                bf16x8 b = ldf(wthb + (of * 16 + lr) * CIN + cf * 32 + lg * 8);
                acc[of] = mfma16(a, b, acc[of]);
            }
        }
        #pragma unroll
        for (int of = 0; of < 8; ++of) {
            int o = of * 16 + lr;
            float sA = bnp[o], sB = bnp[ICH + o];
            #pragma unroll
            for (int r = 0; r < 4; ++r) {
                int q = q0 + lg * 4 + r;
                thn[q * ICH + o] = f2bf(fmaxf(acc[of][r] * sA + sB, 0.f));
            }
        }
    } else if (op == 1) {   // phi = relu(bn(Wph @ x))
        short* phn = phi + (size_t)n * HW * ICH;
        #pragma unroll
        for (int cf = 0; cf < 8; ++cf) {
            bf16x8 a = ldf(Xn + (q0 + lr) * CIN + cf * 32 + lg * 8);
            #pragma unroll
            for (int of = 0; of < 8; ++of) {
                bf16x8 b = ldf(wphb + (of * 16 + lr) * CIN + cf * 32 + lg * 8);
                acc[of] = mfma16(a, b, acc[of]);
            }
        }
        #pragma unroll
        for (int of = 0; of < 8; ++of) {
            int o = of * 16 + lr;
            float sA = bnp[2*ICH + o], sB = bnp[3*ICH + o];
            #pragma unroll
            for (int r = 0; r < 4; ++r) {
                int q = q0 + lg * 4 + r;
                phn[q * ICH + o] = f2bf(fmaxf(acc[of][r] * sA + sB, 0.f));
            }
        }
    } else {                // g = Wg @ x, swapped MFMA roles -> Vt (c,k)
        short* vtn = Vt + (size_t)n * ICH * HW;
        #pragma unroll
        for (int cf = 0; cf < 8; ++cf) {
            bf16x8 bx = ldf(Xn + (q0 + lr) * CIN + cf * 32 + lg * 8);
            #pragma unroll
            for (int mf = 0; mf < 8; ++mf) {
                bf16x8 a = ldf(wgb + (mf * 16 + lr) * CIN + cf * 32 + lg * 8);
                acc[mf] = mfma16(a, bx, acc[mf]);
            }
        }
        #pragma unroll
        for (int mf = 0; mf < 8; ++mf) {
            #pragma unroll
            for (int r = 0; r < 4; ++r) {
                int o = mf * 16 + lg * 4 + r;
                vtn[(size_t)o * HW + q0 + lr] = f2bf(acc[mf][r]);
            }
        }
    }
}

// ---------------------------------------------------------------------------
// K3: flash attention, k-split x6, swapped QK^T -> lane-local softmax +
// in-register P. Software-pipelined: per iteration
//   {loads(t+1) -> softmax(t) -> LDS writes(t+1) -> barrier -> QK(t+1) -> PV(t)}
// so the wave's softmax VALU overlaps the previous iteration's 32 MFMAs.
// K double-buffered, V TRIPLE-buffered (PV(t) reads post-barrier(t); the
// overwrite of its buffer happens at t+3, with barriers t+1, t+2 between).
// V read buf for tile t = t%3 = (vw+2)%3 where vw=(t+1)%3.
// LDS = 2*8K + 3*10.24K = 46.7KB -> 3 blocks/CU; grid 768 = zero tail.
// ---------------------------------------------------------------------------
__global__ __launch_bounds__(256, 3) void k_attn(const short* __restrict__ theta,
                                                 const short* __restrict__ phi,
                                                 const short* __restrict__ Vt,
                                                 short* __restrict__ Op,
                                                 float* __restrict__ Ls) {
    __shared__ char  K_lds[2][8192];        // 32 keys x 128 ch bf16, XOR-swizzled
    __shared__ short V_lds[3][128 * 40];    // 128 ch x 32 keys, stride 40 shorts

    const int bid  = blockIdx.x;
    const int j    = bid & 7;
    const int n    = j >> 1;
    const int rest = ((bid >> 3) << 1) | (j & 1);   // 0..191
    const int qb   = rest / KSPL;                   // 0..31
    const int ks   = rest % KSPL;                   // 0..5
    const int tbase = ks * 21 + (ks < 2 ? ks : 2);  // 0,22,44,65,86,107
    const int tcnt  = 21 + (ks < 2 ? 1 : 0);
    const int tid  = threadIdx.x;
    const int lane = tid & 63;
    const int wave = tid >> 6;
    const int lr = lane & 15, lg = lane >> 4;
    const int q0 = qb * 128 + wave * 32;

    const short* Qn = theta + (size_t)n * HW * ICH;
    const short* Kn = phi   + (size_t)n * HW * ICH;
    const short* Vn = Vt    + (size_t)n * ICH * HW;

    bf16x8 aq[2][4];
    #pragma unroll
    for (int m2 = 0; m2 < 2; ++m2)
        #pragma unroll
        for (int cf = 0; cf < 4; ++cf)
            aq[m2][cf] = ldf(Qn + (q0 + m2 * 16 + lr) * ICH + cf * 32 + lg * 8);

    // O^T accumulators: O[m2][cc] rows c = cc*16+lg*4+r, col q = q0+m2*16+lr
    f32x4 O[2][8];
    #pragma unroll
    for (int m2 = 0; m2 < 2; ++m2)
        #pragma unroll
        for (int i = 0; i < 8; ++i) { O[m2][i][0]=0.f; O[m2][i][1]=0.f; O[m2][i][2]=0.f; O[m2][i][3]=0.f; }
    float mx[2] = { -INFINITY, -INFINITY };
    float l[2]  = { 0.f, 0.f };

    f32x4  s[2][2];     // S^T accumulators, live across the iteration boundary
    bf16x8 pb[2];       // P fragments, live across the barrier
    bf16x8 kr0, kr1, vr0, vr1;

    auto loadK = [&](int tabs) {   // linear coalesced b128; swizzle applied on WRITE
        const char* kc = (const char*)(Kn + (size_t)tabs * KVB * ICH);
        kr0 = *(const bf16x8*)(kc + tid * 16);
        kr1 = *(const bf16x8*)(kc + 4096 + tid * 16);
    };
    auto writeK = [&](int pp) {
        const int o0 = tid * 16;
        const int o1 = 4096 + tid * 16;
        *(bf16x8*)&K_lds[pp][o0 ^ (((o0 >> 8) & 7) << 4)] = kr0;
        *(bf16x8*)&K_lds[pp][o1 ^ (((o1 >> 8) & 7) << 4)] = kr1;
    };
    auto loadV = [&](int tabs) {
        vr0 = ldf(Vn + (size_t)(tid >> 2) * HW + tabs * KVB + (tid & 3) * 8);
        vr1 = ldf(Vn + (size_t)((tid + 256) >> 2) * HW + tabs * KVB + (tid & 3) * 8);
    };
    auto writeV = [&](int pp) {
        *(bf16x8*)&V_lds[pp][(tid >> 2) * 40 + (tid & 3) * 8] = vr0;
        *(bf16x8*)&V_lds[pp][((tid + 256) >> 2) * 40 + (tid & 3) * 8] = vr1;
    };
    auto qk = [&](int pp) {        // s = K(buf pp) @ Q^T, 8 ds_read_b128 + 16 MFMA
        #pragma unroll
        for (int tt = 0; tt < 2; ++tt)
            #pragma unroll
            for (int m2 = 0; m2 < 2; ++m2) { s[tt][m2][0]=0.f; s[tt][m2][1]=0.f; s[tt][m2][2]=0.f; s[tt][m2][3]=0.f; }
        __builtin_amdgcn_s_setprio(1);
        #pragma unroll
        for (int tt = 0; tt < 2; ++tt) {
            const int row = tt * 16 + lr;
            const int rsw = (row & 7) << 4;
            #pragma unroll
            for (int cf = 0; cf < 4; ++cf) {
                bf16x8 kf = *(const bf16x8*)(&K_lds[pp][row * 256 + ((cf * 64 + lg * 16) ^ rsw)]);
                s[tt][0] = mfma16(kf, aq[0][cf], s[tt][0]);
                s[tt][1] = mfma16(kf, aq[1][cf], s[tt][1]);
            }
        }
        __builtin_amdgcn_s_setprio(0);
    };
    auto pv = [&](int pp) {        // O += V(buf pp) @ P, 16 ds_read_b64 + 16 MFMA
        __builtin_amdgcn_s_setprio(1);
        #pragma unroll
        for (int cc = 0; cc < 8; ++cc) {
            const short* vb = &V_lds[pp][(cc * 16 + lr) * 40 + lg * 4];
            bf16x4 va0 = *(const bf16x4*)vb;         // keys lg*4 + 0..3
            bf16x4 va1 = *(const bf16x4*)(vb + 16);  // keys 16 + lg*4 + 0..3
            bf16x8 vf = __builtin_shufflevector(va0, va1, 0, 1, 2, 3, 4, 5, 6, 7);
            O[0][cc] = mfma16(vf, pb[0], O[0][cc]);
            O[1][cc] = mfma16(vf, pb[1], O[1][cc]);
        }
        __builtin_amdgcn_s_setprio(0);
    };

    // prologue: stage tile 0 (Kbuf0, Vbuf0), then QK(0)
    loadK(tbase);
    loadV(tbase);
    writeK(0);
    writeV(0);
    __syncthreads();
    qk(0);

    int vw = 1;   // V write buf for tile t+1; V read buf for tile t = (vw+2)%3
    for (int t = 0; t < tcnt; ++t) {
        const bool pre = (t + 1 < tcnt);
        if (pre) { loadK(tbase + t + 1); loadV(tbase + t + 1); }   // issue-early

        // ---- softmax(t): lane-local, base-2, defer-max THR=11
        float lm[2];
        #pragma unroll
        for (int m2 = 0; m2 < 2; ++m2) {
            float a0 = fmaxf(fmaxf(s[0][m2][0], s[0][m2][1]), fmaxf(s[0][m2][2], s[0][m2][3]));
            float a1 = fmaxf(fmaxf(s[1][m2][0], s[1][m2][1]), fmaxf(s[1][m2][2], s[1][m2][3]));
            lm[m2] = fmaxf(a0, a1);
        }
        int need = (lm[0] > mx[0] + 11.f) || (lm[1] > mx[1] + 11.f);
        if (__any(need)) {
            #pragma unroll
            for (int m2 = 0; m2 < 2; ++m2) {
                float v = lm[m2];
                v = fmaxf(v, __shfl_xor(v, 16));
                v = fmaxf(v, __shfl_xor(v, 32));
                float mn = fmaxf(mx[m2], v);
                float a  = exp2a(mx[m2] - mn);
                mx[m2] = mn;
                l[m2] *= a;
                #pragma unroll
                for (int cc = 0; cc < 8; ++cc) {
                    O[m2][cc][0] *= a; O[m2][cc][1] *= a;
                    O[m2][cc][2] *= a; O[m2][cc][3] *= a;
                }
            }
        }
        #pragma unroll
        for (int m2 = 0; m2 < 2; ++m2) {
            float e[8];
            #pragma unroll
            for (int r = 0; r < 4; ++r) {
                e[r]     = exp2a(s[0][m2][r] - mx[m2]);
                e[4 + r] = exp2a(s[1][m2][r] - mx[m2]);
            }
            l[m2] += ((e[0] + e[1]) + (e[2] + e[3])) + ((e[4] + e[5]) + (e[6] + e[7]));
            union { u32x4 u; bf16x8 b; } cv;
            cv.u[0] = cvtpk(e[0], e[1]);
            cv.u[1] = cvtpk(e[2], e[3]);
            cv.u[2] = cvtpk(e[4], e[5]);
            cv.u[3] = cvtpk(e[6], e[7]);
            pb[m2] = cv.b;
        }

        if (pre) { writeK((t + 1) & 1); writeV(vw); }   // write-late
        __syncthreads();

        if (pre) qk((t + 1) & 1);       // QK(t+1) issued BEFORE PV(t)
        pv(vw == 0 ? 2 : vw - 1);       // PV(t): read buf = t%3 = (vw+2)%3  [r9 bugfix]
        vw = (vw == 2) ? 0 : vw + 1;
    }

    // ---- epilogue: reduce l across lg groups, write partial + lse2
    const size_t obase = (size_t)(ks * NB + n) * HW;
    #pragma unroll
    for (int m2 = 0; m2 < 2; ++m2) {
        float v = l[m2];
        v += __shfl_xor(v, 16);
        v += __shfl_xor(v, 32);
        l[m2] = v;
        const float inv = 1.f / v;
        const int q = q0 + m2 * 16 + lr;
        #pragma unroll
        for (int cc = 0; cc < 8; ++cc) {
            uint2 ov;
            ov.x = cvtpk(O[m2][cc][0] * inv, O[m2][cc][1] * inv);
            ov.y = cvtpk(O[m2][cc][2] * inv, O[m2][cc][3] * inv);
            *(uint2*)&Op[(obase + q) * ICH + cc * 16 + lg * 4] = ov;
        }
        if (lg == 0)
            Ls[obase + q] = mx[m2] + log2a(l[m2]);
    }
}

// ---------------------------------------------------------------------------
// K4: fused combine + final conv + residual.
// Phase 1: 256 threads cooperatively combine the 6 k-split partials into an
// XOR-swizzled LDS tile. Phase 2: MFMA. grid (128, 4) x 256.
// ---------------------------------------------------------------------------
__global__ __launch_bounds__(256) void k_out(const short* __restrict__ Op,
                                             const float* __restrict__ Ls,
                                             const short* __restrict__ wwb,
                                             const float* __restrict__ feat,
                                             float* __restrict__ out) {
    __shared__ char bo_lds[32 * 256];   // 32 q x 128 c bf16, rows 256B, XOR-swizzled
    const int n   = blockIdx.y;
    const int q0  = blockIdx.x * 32;
    const int tid = threadIdx.x;

    // ---- phase 1: combine splits for (q = tid>>3, c = (tid&7)*16 .. +16)
    {
        const int q  = tid >> 3;
        const int c0 = (tid & 7) * 16;
        const int qg = q0 + q;
        float ls[KSPL], M = -INFINITY;
        #pragma unroll
        for (int i = 0; i < KSPL; ++i) {
            ls[i] = Ls[((size_t)(i * NB + n)) * HW + qg];
            M = fmaxf(M, ls[i]);
        }
        float wq[KSPL], ws = 0.f;
        #pragma unroll
        for (int i = 0; i < KSPL; ++i) { wq[i] = exp2a(ls[i] - M); ws += wq[i]; }
        const float inv = 1.f / ws;
        float fo[16];
        #pragma unroll
        for (int e = 0; e < 16; ++e) fo[e] = 0.f;
        #pragma unroll
        for (int i = 0; i < KSPL; ++i) {
            const short* p = Op + ((size_t)(i * NB + n) * HW + qg) * ICH + c0;
            bf16x8 v0 = ldf(p);
            bf16x8 v1 = ldf(p + 8);
            #pragma unroll
            for (int e = 0; e < 8; ++e) {
                fo[e]     += wq[i] * bf2f(v0[e]);
                fo[8 + e] += wq[i] * bf2f(v1[e]);
            }
        }
        const int rsw = (q & 7) << 4;
        u32x4 w0, w1;
        #pragma unroll
        for (int e = 0; e < 4; ++e) {
            w0[e] = cvtpk(fo[2*e] * inv,     fo[2*e+1] * inv);
            w1[e] = cvtpk(fo[8+2*e] * inv,   fo[8+2*e+1] * inv);
        }
        *(u32x4*)&bo_lds[q * 256 + ((c0 * 2) ^ rsw)]        = w0;
        *(u32x4*)&bo_lds[q * 256 + (((c0 + 8) * 2) ^ rsw)]  = w1;
    }
    __syncthreads();

    // ---- phase 2: out[o, q] = ww @ bO + residual
    const int wave = tid >> 6;
    const int lane = tid & 63;
    const int lr = lane & 15, lg = lane >> 4;
    const int o0 = wave * 64;

    f32x4 acc[4][2];
    #pragma unroll
    for (int i = 0; i < 4; ++i)
        #pragma unroll
        for (int jn = 0; jn < 2; ++jn) { acc[i][jn][0]=0.f; acc[i][jn][1]=0.f; acc[i][jn][2]=0.f; acc[i][jn][3]=0.f; }

    #pragma unroll
    for (int cf = 0; cf < 4; ++cf) {
        bf16x8 bO[2];
        #pragma unroll
        for (int nf = 0; nf < 2; ++nf) {
            const int row = nf * 16 + lr;
            const int byt = (cf * 64 + lg * 16) ^ ((row & 7) << 4);
            bO[nf] = *(const bf16x8*)&bo_lds[row * 256 + byt];
        }
        #pragma unroll
        for (int mf = 0; mf < 4; ++mf) {
            bf16x8 a = ldf(wwb + (o0 + mf * 16 + lr) * ICH + cf * 32 + lg * 8);
            #pragma unroll
            for (int nf = 0; nf < 2; ++nf)
                acc[mf][nf] = mfma16(a, bO[nf], acc[mf][nf]);
        }
    }
    #pragma unroll
    for (int mf = 0; mf < 4; ++mf) {
        #pragma unroll
        for (int nf = 0; nf < 2; ++nf) {
            #pragma unroll
            for (int r = 0; r < 4; ++r) {
                int o = o0 + mf * 16 + lg * 4 + r;
                int q = q0 + nf * 16 + lr;
                long long cxi = (((long long)(n * CIN + o)) * 9 + 5) * HW + q;
                out[((long long)(n * CIN + o)) * HW + q] = acc[mf][nf][r] + feat[cxi];
            }
        }
    }
}

// ---------------------------------------------------------------------------
extern "C" void kernel_launch(void* const* d_in, const int* in_sizes, int n_in,
                              void* d_out, int out_size, void* d_ws, size_t ws_size,
                              hipStream_t stream) {
    const float* feat = (const float*)d_in[0];
    const float* wth  = (const float*)d_in[1];
    const float* gth  = (const float*)d_in[2];
    const float* bth  = (const float*)d_in[3];
    const float* mth  = (const float*)d_in[4];
    const float* vth  = (const float*)d_in[5];
    const float* wph  = (const float*)d_in[6];
    const float* gph  = (const float*)d_in[7];
    const float* bph  = (const float*)d_in[8];
    const float* mph  = (const float*)d_in[9];
    const float* vph  = (const float*)d_in[10];
    const float* wg   = (const float*)d_in[11];
    const float* ww   = (const float*)d_in[12];
    float* out = (float*)d_out;

    size_t off = 0;
    auto carve = [&](size_t bytes) {
        void* p = (char*)d_ws + off;
        off += (bytes + 255) & ~(size_t)255;
        return p;
    };
    short* Xbf   = (short*)carve((size_t)NB * HW * CIN * 2);
    short* CXbf  = (short*)carve((size_t)NB * HW * CIN * 2);
    short* theta = (short*)carve((size_t)NB * HW * ICH * 2);
    short* phi   = (short*)carve((size_t)NB * HW * ICH * 2);
    short* Vt    = (short*)carve((size_t)NB * ICH * HW * 2);
    short* Op    = (short*)carve((size_t)KSPL * NB * HW * ICH * 2);
    float* Ls    = (float*)carve((size_t)KSPL * NB * HW * 4);
    short* wthb  = (short*)carve((size_t)ICH * CIN * 2);
    short* wphb  = (short*)carve((size_t)ICH * CIN * 2);
    short* wgb   = (short*)carve((size_t)ICH * CIN * 2);
    short* wwb   = (short*)carve((size_t)CIN * ICH * 2);
    float* bnp   = (float*)carve((size_t)4 * ICH * 4);

    k_prep_x<<<dim3(64, 8, NB), 256, 0, stream>>>(feat, Xbf, CXbf,
                                                  wth, wph, wg, ww,
                                                  gth, bth, mth, vth,
                                                  gph, bph, mph, vph,
                                                  wthb, wphb, wgb, wwb, bnp);
    k_conv3<<<dim3(64, NB, 3), 256, 0, stream>>>(Xbf, CXbf, wthb, wphb, wgb, bnp,
                                                 theta, phi, Vt);
    k_attn<<<768, 256, 0, stream>>>(theta, phi, Vt, Op, Ls);
    k_out<<<dim3(128, NB), 256, 0, stream>>>(Op, Ls, wwb, feat, out);
}

// Round 11
// 113.995 us; speedup vs baseline: 2.4683x; 1.0051x over previous
//
#include <hip/hip_runtime.h>
#include <math.h>

#define HW   4096
#define CIN  256
#define ICH  128
#define NB   4
#define KSPL 6      // 6 uneven k-splits: grid 32*6*4 = 768 = 3 blocks/CU exactly
#define KVB  32

typedef __attribute__((ext_vector_type(4))) float f32x4;
typedef __attribute__((ext_vector_type(8))) short bf16x8;
typedef __attribute__((ext_vector_type(4))) short bf16x4;
typedef __attribute__((ext_vector_type(4))) unsigned u32x4;

__device__ inline short f2bf(float f) {
    unsigned int u = __float_as_uint(f);
    u += 0x7fffU + ((u >> 16) & 1U);   // round-to-nearest-even
    return (short)(u >> 16);
}

__device__ inline float bf2f(short s) {
    return __uint_as_float(((unsigned int)(unsigned short)s) << 16);
}

__device__ inline float exp2a(float x) {  // 2^x, handles -inf -> 0
    float r;
    asm("v_exp_f32 %0, %1" : "=v"(r) : "v"(x));
    return r;
}
__device__ inline float log2a(float x) {
    float r;
    asm("v_log_f32 %0, %1" : "=v"(r) : "v"(x));
    return r;
}
__device__ inline unsigned cvtpk(float a, float b) {  // lo=bf16(a), hi=bf16(b), RNE
    unsigned r;
    asm("v_cvt_pk_bf16_f32 %0, %1, %2" : "=v"(r) : "v"(a), "v"(b));
    return r;
}

__device__ inline f32x4 mfma16(bf16x8 a, bf16x8 b, f32x4 c) {
    return __builtin_amdgcn_mfma_f32_16x16x32_bf16(a, b, c, 0, 0, 0);
}

__device__ inline bf16x8 ldf(const short* p) { return *(const bf16x8*)p; }

// ---------------------------------------------------------------------------
// K1: x = max_d(feature), cx = feature[:, :, 5]; write (n,q,c) bf16.
// Blocks with blockIdx.y==0 additionally convert the 4 weight matrices to
// bf16 and (block 0) fold the BN params.
// ---------------------------------------------------------------------------
__global__ __launch_bounds__(256) void k_prep_x(const float* __restrict__ feat,
                                                short* __restrict__ Xbf,
                                                short* __restrict__ CXbf,
                                                const float* __restrict__ wth,
                                                const float* __restrict__ wph,
                                                const float* __restrict__ wg,
                                                const float* __restrict__ ww,
                                                const float* __restrict__ gth,
                                                const float* __restrict__ bth,
                                                const float* __restrict__ mth,
                                                const float* __restrict__ vth,
                                                const float* __restrict__ gph,
                                                const float* __restrict__ bph,
                                                const float* __restrict__ mph,
                                                const float* __restrict__ vph,
                                                short* __restrict__ wthb,
                                                short* __restrict__ wphb,
                                                short* __restrict__ wgb,
                                                short* __restrict__ wwb,
                                                float* __restrict__ bnp) {
    const float LOG2E = 1.44269504f;
    const int q0 = blockIdx.x * 64;
    const int c0 = blockIdx.y * 32;
    const int n  = blockIdx.z;
    __shared__ float xs[32][68];
    __shared__ float cxs[32][68];
    const int tid = threadIdx.x;

    // ---- fused weight prep (256 blocks with y==0; 128 elems/matrix each)
    if (blockIdx.y == 0) {
        const int wid = blockIdx.x + 64 * n;       // 0..255
        const int i = wid * 128 + (tid & 127);
        if (tid < 128) {
            wthb[i] = f2bf(wth[i]);
            wphb[i] = f2bf(wph[i]);
        } else {
            wgb[i] = f2bf(wg[i]);
            wwb[i] = f2bf(ww[i]);
        }
        if (wid == 0 && tid < ICH) {
            int o = tid;
            float s1 = gth[o] * rsqrtf(vth[o] + 1e-5f);
            bnp[o]        = s1 * LOG2E;
            bnp[ICH + o]  = (bth[o] - mth[o] * s1) * LOG2E;
            float s2 = gph[o] * rsqrtf(vph[o] + 1e-5f);
            bnp[2*ICH + o] = s2;
            bnp[3*ICH + o] = bph[o] - mph[o] * s2;
        }
    }

    const int qv  = (tid & 15) * 4;
    const int ci  = tid >> 4;          // 0..15

    #pragma unroll
    for (int h = 0; h < 2; ++h) {
        const int cc = h * 16 + ci;
        const float* fp = feat + ((size_t)(n * CIN + c0 + cc)) * 9 * HW + q0 + qv;
        float4 mx = *(const float4*)fp;
        float4 cx = make_float4(0.f, 0.f, 0.f, 0.f);
        #pragma unroll
        for (int d = 1; d < 9; ++d) {
            float4 v = *(const float4*)(fp + (size_t)d * HW);
            if (d == 5) cx = v;
            mx.x = fmaxf(mx.x, v.x); mx.y = fmaxf(mx.y, v.y);
            mx.z = fmaxf(mx.z, v.z); mx.w = fmaxf(mx.w, v.w);
        }
        *(float4*)&xs[cc][qv]  = mx;
        *(float4*)&cxs[cc][qv] = cx;
    }
    __syncthreads();
    #pragma unroll
    for (int it = 0; it < 2; ++it) {
        const int q  = it * 32 + (tid >> 3);
        const int cq = (tid & 7) * 4;
        ushort4 ox, oc;
        ox.x = (unsigned short)f2bf(xs[cq][q]);
        ox.y = (unsigned short)f2bf(xs[cq + 1][q]);
        ox.z = (unsigned short)f2bf(xs[cq + 2][q]);
        ox.w = (unsigned short)f2bf(xs[cq + 3][q]);
        oc.x = (unsigned short)f2bf(cxs[cq][q]);
        oc.y = (unsigned short)f2bf(cxs[cq + 1][q]);
        oc.z = (unsigned short)f2bf(cxs[cq + 2][q]);
        oc.w = (unsigned short)f2bf(cxs[cq + 3][q]);
        const size_t ob = ((size_t)n * HW + q0 + q) * CIN + c0 + cq;
        *(ushort4*)&Xbf[ob]  = ox;
        *(ushort4*)&CXbf[ob] = oc;
    }
}

// ---------------------------------------------------------------------------
// K2: one of {theta, phi, g} per blockIdx.z -> grid (64, 4, 3) = 768 blocks.
// theta/phi (q,c) with BN+ReLU; g with swapped roles -> Vt (c,k).
// ---------------------------------------------------------------------------
__global__ __launch_bounds__(256) void k_conv3(const short* __restrict__ Xbf,
                                               const short* __restrict__ CXbf,
                                               const short* __restrict__ wthb,
                                               const short* __restrict__ wphb,
                                               const short* __restrict__ wgb,
                                               const float* __restrict__ bnp,
                                               short* __restrict__ theta,
                                               short* __restrict__ phi,
                                               short* __restrict__ Vt) {
    const int n    = blockIdx.y;
    const int op   = blockIdx.z;
    const int wave = threadIdx.x >> 6;
    const int lane = threadIdx.x & 63;
    const int lr = lane & 15, lg = lane >> 4;
    const int q0 = blockIdx.x * 64 + wave * 16;
    const short* Xn  = Xbf  + (size_t)n * HW * CIN;
    const short* CXn = CXbf + (size_t)n * HW * CIN;

    f32x4 acc[8];
    #pragma unroll
    for (int i = 0; i < 8; ++i) { acc[i][0]=0.f; acc[i][1]=0.f; acc[i][2]=0.f; acc[i][3]=0.f; }

    if (op == 0) {          // theta = relu(bn(Wth @ cx))
        short* thn = theta + (size_t)n * HW * ICH;
        #pragma unroll
        for (int cf = 0; cf < 8; ++cf) {
            bf16x8 a = ldf(CXn + (q0 + lr) * CIN + cf * 32 + lg * 8);
            #pragma unroll
            for (int of = 0; of < 8; ++of) {
                bf16x8 b = ldf(wthb + (of * 16 + lr) * CIN + cf * 32 + lg * 8);
                acc[of] = mfma16(a, b, acc[of]);
            }
        }
        #pragma unroll
        for (int of = 0; of < 8; ++of) {
            int o = of * 16 + lr;
            float sA = bnp[o], sB = bnp[ICH + o];
            #pragma unroll
            for (int r = 0; r < 4; ++r) {
                int q = q0 + lg * 4 + r;
                thn[q * ICH + o] = f2bf(fmaxf(acc[of][r] * sA + sB, 0.f));
            }
        }
    } else if (op == 1) {   // phi = relu(bn(Wph @ x))
        short* phn = phi + (size_t)n * HW * ICH;
        #pragma unroll
        for (int cf = 0; cf < 8; ++cf) {
            bf16x8 a = ldf(Xn + (q0 + lr) * CIN + cf * 32 + lg * 8);
            #pragma unroll
            for (int of = 0; of < 8; ++of) {
                bf16x8 b = ldf(wphb + (of * 16 + lr) * CIN + cf * 32 + lg * 8);
                acc[of] = mfma16(a, b, acc[of]);
            }
        }
        #pragma unroll
        for (int of = 0; of < 8; ++of) {
            int o = of * 16 + lr;
            float sA = bnp[2*ICH + o], sB = bnp[3*ICH + o];
            #pragma unroll
            for (int r = 0; r < 4; ++r) {
                int q = q0 + lg * 4 + r;
                phn[q * ICH + o] = f2bf(fmaxf(acc[of][r] * sA + sB, 0.f));
            }
        }
    } else {                // g = Wg @ x, swapped MFMA roles -> Vt (c,k)
        short* vtn = Vt + (size_t)n * ICH * HW;
        #pragma unroll
        for (int cf = 0; cf < 8; ++cf) {
            bf16x8 bx = ldf(Xn + (q0 + lr) * CIN + cf * 32 + lg * 8);
            #pragma unroll
            for (int mf = 0; mf < 8; ++mf) {
                bf16x8 a = ldf(wgb + (mf * 16 + lr) * CIN + cf * 32 + lg * 8);
                acc[mf] = mfma16(a, bx, acc[mf]);
            }
        }
        #pragma unroll
        for (int mf = 0; mf < 8; ++mf) {
            #pragma unroll
            for (int r = 0; r < 4; ++r) {
                int o = mf * 16 + lg * 4 + r;
                vtn[(size_t)o * HW + q0 + lr] = f2bf(acc[mf][r]);
            }
        }
    }
}

// ---------------------------------------------------------------------------
// K3: flash attention, k-split x6, swapped QK^T -> lane-local softmax +
// in-register P. Software-pipelined: per iteration
//   {loads(t+1) -> softmax(t) -> LDS writes(t+1) -> barrier -> QK(t+1) -> PV(t)}
// l accumulated on the MFMA pipe via an all-ones A-fragment (lacc); the MFMA
// sums the full K=32 of each tile, so no per-lane partials and no epilogue
// cross-lane reduce. max tree grouped in triples for v_max3 fusion.
// K double-buffered, V TRIPLE-buffered; V read buf for tile t = (vw+2)%3.
// LDS = 2*8K + 3*10.24K = 46.7KB -> 3 blocks/CU; grid 768 = zero tail.
// ---------------------------------------------------------------------------
__global__ __launch_bounds__(256, 3) void k_attn(const short* __restrict__ theta,
                                                 const short* __restrict__ phi,
                                                 const short* __restrict__ Vt,
                                                 short* __restrict__ Op,
                                                 float* __restrict__ Ls) {
    __shared__ char  K_lds[2][8192];        // 32 keys x 128 ch bf16, XOR-swizzled
    __shared__ short V_lds[3][128 * 40];    // 128 ch x 32 keys, stride 40 shorts

    const int bid  = blockIdx.x;
    const int j    = bid & 7;
    const int n    = j >> 1;
    const int rest = ((bid >> 3) << 1) | (j & 1);   // 0..191
    const int qb   = rest / KSPL;                   // 0..31
    const int ks   = rest % KSPL;                   // 0..5
    const int tbase = ks * 21 + (ks < 2 ? ks : 2);  // 0,22,44,65,86,107
    const int tcnt  = 21 + (ks < 2 ? 1 : 0);
    const int tid  = threadIdx.x;
    const int lane = tid & 63;
    const int wave = tid >> 6;
    const int lr = lane & 15, lg = lane >> 4;
    const int q0 = qb * 128 + wave * 32;

    const short* Qn = theta + (size_t)n * HW * ICH;
    const short* Kn = phi   + (size_t)n * HW * ICH;
    const short* Vn = Vt    + (size_t)n * ICH * HW;

    bf16x8 aq[2][4];
    #pragma unroll
    for (int m2 = 0; m2 < 2; ++m2)
        #pragma unroll
        for (int cf = 0; cf < 4; ++cf)
            aq[m2][cf] = ldf(Qn + (q0 + m2 * 16 + lr) * ICH + cf * 32 + lg * 8);

    const short BF1 = (short)0x3F80;   // bf16 1.0
    const bf16x8 vones = { BF1, BF1, BF1, BF1, BF1, BF1, BF1, BF1 };

    // O^T accumulators: O[m2][cc] rows c = cc*16+lg*4+r, col q = q0+m2*16+lr
    f32x4 O[2][8];
    #pragma unroll
    for (int m2 = 0; m2 < 2; ++m2)
        #pragma unroll
        for (int i = 0; i < 8; ++i) { O[m2][i][0]=0.f; O[m2][i][1]=0.f; O[m2][i][2]=0.f; O[m2][i][3]=0.f; }
    f32x4 lacc[2];   // l via ones-MFMA: every reg = sum_k P[k][q=lr]
    lacc[0][0]=0.f; lacc[0][1]=0.f; lacc[0][2]=0.f; lacc[0][3]=0.f;
    lacc[1][0]=0.f; lacc[1][1]=0.f; lacc[1][2]=0.f; lacc[1][3]=0.f;
    float mx[2] = { -INFINITY, -INFINITY };

    f32x4  s[2][2];     // S^T accumulators, live across the iteration boundary
    bf16x8 pb[2];       // P fragments, live across the barrier
    bf16x8 kr0, kr1, vr0, vr1;

    auto loadK = [&](int tabs) {   // linear coalesced b128; swizzle applied on WRITE
        const char* kc = (const char*)(Kn + (size_t)tabs * KVB * ICH);
        kr0 = *(const bf16x8*)(kc + tid * 16);
        kr1 = *(const bf16x8*)(kc + 4096 + tid * 16);
    };
    auto writeK = [&](int pp) {
        const int o0 = tid * 16;
        const int o1 = 4096 + tid * 16;
        *(bf16x8*)&K_lds[pp][o0 ^ (((o0 >> 8) & 7) << 4)] = kr0;
        *(bf16x8*)&K_lds[pp][o1 ^ (((o1 >> 8) & 7) << 4)] = kr1;
    };
    auto loadV = [&](int tabs) {
        vr0 = ldf(Vn + (size_t)(tid >> 2) * HW + tabs * KVB + (tid & 3) * 8);
        vr1 = ldf(Vn + (size_t)((tid + 256) >> 2) * HW + tabs * KVB + (tid & 3) * 8);
    };
    auto writeV = [&](int pp) {
        *(bf16x8*)&V_lds[pp][(tid >> 2) * 40 + (tid & 3) * 8] = vr0;
        *(bf16x8*)&V_lds[pp][((tid + 256) >> 2) * 40 + (tid & 3) * 8] = vr1;
    };
    auto qk = [&](int pp) {        // s = K(buf pp) @ Q^T, 8 ds_read_b128 + 16 MFMA
        #pragma unroll
        for (int tt = 0; tt < 2; ++tt)
            #pragma unroll
            for (int m2 = 0; m2 < 2; ++m2) { s[tt][m2][0]=0.f; s[tt][m2][1]=0.f; s[tt][m2][2]=0.f; s[tt][m2][3]=0.f; }
        __builtin_amdgcn_s_setprio(1);
        #pragma unroll
        for (int tt = 0; tt < 2; ++tt) {
            const int row = tt * 16 + lr;
            const int rsw = (row & 7) << 4;
            #pragma unroll
            for (int cf = 0; cf < 4; ++cf) {
                bf16x8 kf = *(const bf16x8*)(&K_lds[pp][row * 256 + ((cf * 64 + lg * 16) ^ rsw)]);
                s[tt][0] = mfma16(kf, aq[0][cf], s[tt][0]);
                s[tt][1] = mfma16(kf, aq[1][cf], s[tt][1]);
            }
        }
        __builtin_amdgcn_s_setprio(0);
    };
    auto pv = [&](int pp) {        // O += V(buf pp) @ P; l += ones @ P
        __builtin_amdgcn_s_setprio(1);
        #pragma unroll
        for (int cc = 0; cc < 8; ++cc) {
            const short* vb = &V_lds[pp][(cc * 16 + lr) * 40 + lg * 4];
            bf16x4 va0 = *(const bf16x4*)vb;         // keys lg*4 + 0..3
            bf16x4 va1 = *(const bf16x4*)(vb + 16);  // keys 16 + lg*4 + 0..3
            bf16x8 vf = __builtin_shufflevector(va0, va1, 0, 1, 2, 3, 4, 5, 6, 7);
            O[0][cc] = mfma16(vf, pb[0], O[0][cc]);
            O[1][cc] = mfma16(vf, pb[1], O[1][cc]);
        }
        lacc[0] = mfma16(vones, pb[0], lacc[0]);
        lacc[1] = mfma16(vones, pb[1], lacc[1]);
        __builtin_amdgcn_s_setprio(0);
    };

    // prologue: stage tile 0 (Kbuf0, Vbuf0), then QK(0)
    loadK(tbase);
    loadV(tbase);
    writeK(0);
    writeV(0);
    __syncthreads();
    qk(0);

    int vw = 1;   // V write buf for tile t+1; V read buf for tile t = (vw+2)%3
    for (int t = 0; t < tcnt; ++t) {
        const bool pre = (t + 1 < tcnt);
        if (pre) { loadK(tbase + t + 1); loadV(tbase + t + 1); }   // issue-early

        // ---- softmax(t): lane-local, base-2, defer-max THR=11
        float lm[2];
        #pragma unroll
        for (int m2 = 0; m2 < 2; ++m2) {   // triples -> v_max3 fusion
            float t1 = fmaxf(fmaxf(s[0][m2][0], s[0][m2][1]), s[0][m2][2]);
            float t2 = fmaxf(fmaxf(s[0][m2][3], s[1][m2][0]), s[1][m2][1]);
            float t3 = fmaxf(fmaxf(s[1][m2][2], s[1][m2][3]), t1);
            lm[m2] = fmaxf(t2, t3);
        }
        int need = (lm[0] > mx[0] + 11.f) || (lm[1] > mx[1] + 11.f);
        if (__any(need)) {
            #pragma unroll
            for (int m2 = 0; m2 < 2; ++m2) {
                float v = lm[m2];
                v = fmaxf(v, __shfl_xor(v, 16));
                v = fmaxf(v, __shfl_xor(v, 32));
                float mn = fmaxf(mx[m2], v);
                float a  = exp2a(mx[m2] - mn);
                mx[m2] = mn;
                lacc[m2][0] *= a; lacc[m2][1] *= a;
                lacc[m2][2] *= a; lacc[m2][3] *= a;
                #pragma unroll
                for (int cc = 0; cc < 8; ++cc) {
                    O[m2][cc][0] *= a; O[m2][cc][1] *= a;
                    O[m2][cc][2] *= a; O[m2][cc][3] *= a;
                }
            }
        }
        #pragma unroll
        for (int m2 = 0; m2 < 2; ++m2) {
            float e[8];
            #pragma unroll
            for (int r = 0; r < 4; ++r) {
                e[r]     = exp2a(s[0][m2][r] - mx[m2]);
                e[4 + r] = exp2a(s[1][m2][r] - mx[m2]);
            }
            union { u32x4 u; bf16x8 b; } cv;
            cv.u[0] = cvtpk(e[0], e[1]);
            cv.u[1] = cvtpk(e[2], e[3]);
            cv.u[2] = cvtpk(e[4], e[5]);
            cv.u[3] = cvtpk(e[6], e[7]);
            pb[m2] = cv.b;
        }

        if (pre) { writeK((t + 1) & 1); writeV(vw); }   // write-late
        __syncthreads();

        if (pre) qk((t + 1) & 1);       // QK(t+1) issued BEFORE PV(t)
        pv(vw == 0 ? 2 : vw - 1);       // PV(t): read buf = t%3 = (vw+2)%3
        vw = (vw == 2) ? 0 : vw + 1;
    }

    // ---- epilogue: lacc already holds full per-q l (no cross-lane reduce)
    const size_t obase = (size_t)(ks * NB + n) * HW;
    #pragma unroll
    for (int m2 = 0; m2 < 2; ++m2) {
        const float lv = lacc[m2][0];
        const float inv = 1.f / lv;
        const int q = q0 + m2 * 16 + lr;
        #pragma unroll
        for (int cc = 0; cc < 8; ++cc) {
            uint2 ov;
            ov.x = cvtpk(O[m2][cc][0] * inv, O[m2][cc][1] * inv);
            ov.y = cvtpk(O[m2][cc][2] * inv, O[m2][cc][3] * inv);
            *(uint2*)&Op[(obase + q) * ICH + cc * 16 + lg * 4] = ov;
        }
        if (lg == 0)
            Ls[obase + q] = mx[m2] + log2a(lv);
    }
}

// ---------------------------------------------------------------------------
// K4: fused combine + final conv + residual.
// Phase 1: 256 threads cooperatively combine the 6 k-split partials into an
// XOR-swizzled LDS tile. Phase 2: MFMA. grid (128, 4) x 256.
// ---------------------------------------------------------------------------
__global__ __launch_bounds__(256) void k_out(const short* __restrict__ Op,
                                             const float* __restrict__ Ls,
                                             const short* __restrict__ wwb,
                                             const float* __restrict__ feat,
                                             float* __restrict__ out) {
    __shared__ char bo_lds[32 * 256];   // 32 q x 128 c bf16, rows 256B, XOR-swizzled
    const int n   = blockIdx.y;
    const int q0  = blockIdx.x * 32;
    const int tid = threadIdx.x;

    // ---- phase 1: combine splits for (q = tid>>3, c = (tid&7)*16 .. +16)
    {
        const int q  = tid >> 3;
        const int c0 = (tid & 7) * 16;
        const int qg = q0 + q;
        float ls[KSPL], M = -INFINITY;
        #pragma unroll
        for (int i = 0; i < KSPL; ++i) {
            ls[i] = Ls[((size_t)(i * NB + n)) * HW + qg];
            M = fmaxf(M, ls[i]);
        }
        float wq[KSPL], ws = 0.f;
        #pragma unroll
        for (int i = 0; i < KSPL; ++i) { wq[i] = exp2a(ls[i] - M); ws += wq[i]; }
        const float inv = 1.f / ws;
        float fo[16];
        #pragma unroll
        for (int e = 0; e < 16; ++e) fo[e] = 0.f;
        #pragma unroll
        for (int i = 0; i < KSPL; ++i) {
            const short* p = Op + ((size_t)(i * NB + n) * HW + qg) * ICH + c0;
            bf16x8 v0 = ldf(p);
            bf16x8 v1 = ldf(p + 8);
            #pragma unroll
            for (int e = 0; e < 8; ++e) {
                fo[e]     += wq[i] * bf2f(v0[e]);
                fo[8 + e] += wq[i] * bf2f(v1[e]);
            }
        }
        const int rsw = (q & 7) << 4;
        u32x4 w0, w1;
        #pragma unroll
        for (int e = 0; e < 4; ++e) {
            w0[e] = cvtpk(fo[2*e] * inv,     fo[2*e+1] * inv);
            w1[e] = cvtpk(fo[8+2*e] * inv,   fo[8+2*e+1] * inv);
        }
        *(u32x4*)&bo_lds[q * 256 + ((c0 * 2) ^ rsw)]        = w0;
        *(u32x4*)&bo_lds[q * 256 + (((c0 + 8) * 2) ^ rsw)]  = w1;
    }
    __syncthreads();

    // ---- phase 2: out[o, q] = ww @ bO + residual
    const int wave = tid >> 6;
    const int lane = tid & 63;
    const int lr = lane & 15, lg = lane >> 4;
    const int o0 = wave * 64;

    f32x4 acc[4][2];
    #pragma unroll
    for (int i = 0; i < 4; ++i)
        #pragma unroll
        for (int jn = 0; jn < 2; ++jn) { acc[i][jn][0]=0.f; acc[i][jn][1]=0.f; acc[i][jn][2]=0.f; acc[i][jn][3]=0.f; }

    #pragma unroll
    for (int cf = 0; cf < 4; ++cf) {
        bf16x8 bO[2];
        #pragma unroll
        for (int nf = 0; nf < 2; ++nf) {
            const int row = nf * 16 + lr;
            const int byt = (cf * 64 + lg * 16) ^ ((row & 7) << 4);
            bO[nf] = *(const bf16x8*)&bo_lds[row * 256 + byt];
        }
        #pragma unroll
        for (int mf = 0; mf < 4; ++mf) {
            bf16x8 a = ldf(wwb + (o0 + mf * 16 + lr) * ICH + cf * 32 + lg * 8);
            #pragma unroll
            for (int nf = 0; nf < 2; ++nf)
                acc[mf][nf] = mfma16(a, bO[nf], acc[mf][nf]);
        }
    }
    #pragma unroll
    for (int mf = 0; mf < 4; ++mf) {
        #pragma unroll
        for (int nf = 0; nf < 2; ++nf) {
            #pragma unroll
            for (int r = 0; r < 4; ++r) {
                int o = o0 + mf * 16 + lg * 4 + r;
                int q = q0 + nf * 16 + lr;
                long long cxi = (((long long)(n * CIN + o)) * 9 + 5) * HW + q;
                out[((long long)(n * CIN + o)) * HW + q] = acc[mf][nf][r] + feat[cxi];
            }
        }
    }
}

// ---------------------------------------------------------------------------
extern "C" void kernel_launch(void* const* d_in, const int* in_sizes, int n_in,
                              void* d_out, int out_size, void* d_ws, size_t ws_size,
                              hipStream_t stream) {
    const float* feat = (const float*)d_in[0];
    const float* wth  = (const float*)d_in[1];
    const float* gth  = (const float*)d_in[2];
    const float* bth  = (const float*)d_in[3];
    const float* mth  = (const float*)d_in[4];
    const float* vth  = (const float*)d_in[5];
    const float* wph  = (const float*)d_in[6];
    const float* gph  = (const float*)d_in[7];
    const float* bph  = (const float*)d_in[8];
    const float* mph  = (const float*)d_in[9];
    const float* vph  = (const float*)d_in[10];
    const float* wg   = (const float*)d_in[11];
    const float* ww   = (const float*)d_in[12];
    float* out = (float*)d_out;

    size_t off = 0;
    auto carve = [&](size_t bytes) {
        void* p = (char*)d_ws + off;
        off += (bytes + 255) & ~(size_t)255;
        return p;
    };
    short* Xbf   = (short*)carve((size_t)NB * HW * CIN * 2);
    short* CXbf  = (short*)carve((size_t)NB * HW * CIN * 2);
    short* theta = (short*)carve((size_t)NB * HW * ICH * 2);
    short* phi   = (short*)carve((size_t)NB * HW * ICH * 2);
    short* Vt    = (short*)carve((size_t)NB * ICH * HW * 2);
    short* Op    = (short*)carve((size_t)KSPL * NB * HW * ICH * 2);
    float* Ls    = (float*)carve((size_t)KSPL * NB * HW * 4);
    short* wthb  = (short*)carve((size_t)ICH * CIN * 2);
    short* wphb  = (short*)carve((size_t)ICH * CIN * 2);
    short* wgb   = (short*)carve((size_t)ICH * CIN * 2);
    short* wwb   = (short*)carve((size_t)CIN * ICH * 2);
    float* bnp   = (float*)carve((size_t)4 * ICH * 4);

    k_prep_x<<<dim3(64, 8, NB), 256, 0, stream>>>(feat, Xbf, CXbf,
                                                  wth, wph, wg, ww,
                                                  gth, bth, mth, vth,
                                                  gph, bph, mph, vph,
                                                  wthb, wphb, wgb, wwb, bnp);
    k_conv3<<<dim3(64, NB, 3), 256, 0, stream>>>(Xbf, CXbf, wthb, wphb, wgb, bnp,
                                                 theta, phi, Vt);
    k_attn<<<768, 256, 0, stream>>>(theta, phi, Vt, Op, Ls);
    k_out<<<dim3(128, NB), 256, 0, stream>>>(Op, Ls, wwb, feat, out);
}